// Round 3
// baseline (6717.056 us; speedup 1.0000x reference)
//
#include <hip/hip_runtime.h>
#include <stdint.h>

typedef unsigned short u16;
typedef unsigned int u32;

#define SS 4096
#define DD 768
#define NROWS 8192   // B*S

__device__ __forceinline__ float bf2f(u16 u){
  union { u32 u; float f; } x; x.u = ((u32)u) << 16; return x.f;
}
__device__ __forceinline__ u16 f2bf(float f){
  union { float f; u32 u; } x; x.f = f;
  u32 r = x.u + 0x7fffu + ((x.u >> 16) & 1u);
  return (u16)(r >> 16);
}
__device__ __forceinline__ float bflo(u32 u){ union { u32 u; float f; } x; x.u = u << 16; return x.f; }
__device__ __forceinline__ float bfhi(u32 u){ union { u32 u; float f; } x; x.u = u & 0xffff0000u; return x.f; }

// flag==1: external float tensors are fp32; flag==0: they are bf16
__device__ __forceinline__ float ldany(const void* p, size_t i, int f){
  return f ? ((const float*)p)[i] : bf2f(((const u16*)p)[i]);
}

// ---------------------------------------------------------------- dtype detect
__global__ void detect_k(const void* anw, int* flag){
  if (threadIdx.x == 0 && blockIdx.x == 0)
    flag[0] = (((const u32*)anw)[0] == 0x3F800000u) ? 1 : 0;
}

// ---------------------------------------------------------------- transpose (any-float in -> bf16 out)
__global__ void transpose_k(const void* __restrict__ in, size_t ioff,
                            u16* __restrict__ out, int R, int C, const int* fl){
  int f = *fl;
  __shared__ u16 t[32][33];
  int c0 = blockIdx.x * 32, r0 = blockIdx.y * 32;
  int tx = threadIdx.x & 31, ty = threadIdx.x >> 5; // 32x8
  #pragma unroll
  for (int i = 0; i < 32; i += 8){
    int r = r0 + ty + i, c = c0 + tx;
    t[ty + i][tx] = (r < R && c < C) ? f2bf(ldany(in, ioff + (size_t)r * C + c, f)) : (u16)0;
  }
  __syncthreads();
  #pragma unroll
  for (int i = 0; i < 32; i += 8){
    int r = c0 + ty + i, c = r0 + tx;
    if (r < C && c < R) out[(size_t)r * R + c] = t[tx][ty + i];
  }
}

// ---------------------------------------------------------------- embed + id bits
__global__ void embed_k(const int* __restrict__ x, const int* __restrict__ idv,
                        const void* __restrict__ table, u16* __restrict__ xin,
                        const int* fl){
  int f = *fl;
  int row = blockIdx.x;
  int tok = x[row], idval = idv[row];
  for (int j = threadIdx.x; j < 288; j += 256){
    u16 o;
    if (j < 256) o = f2bf(ldany(table, (size_t)tok*256 + j, f) * 16.0f);   // * sqrt(DV)
    else o = ((idval >> (31 - (j - 256))) & 1) ? (u16)0x3F80 : (u16)0;
    xin[(size_t)row * 288 + j] = o;
  }
}

// ---------------------------------------------------------------- per-row rms scale (h is bf16, ours)
__global__ void rowscale_k(const u16* __restrict__ h, float* __restrict__ s){
  int row = blockIdx.x;
  const u16* xp = h + (size_t)row * DD;
  float ss = 0.f;
  for (int i = threadIdx.x; i < DD; i += 256){ float v = bf2f(xp[i]); ss += v*v; }
  #pragma unroll
  for (int off = 32; off > 0; off >>= 1) ss += __shfl_down(ss, off, 64);
  __shared__ float red[4];
  int lane = threadIdx.x & 63, wv = threadIdx.x >> 6;
  if (lane == 0) red[wv] = ss;
  __syncthreads();
  if (threadIdx.x == 0){
    float tot = red[0] + red[1] + red[2] + red[3];
    s[row] = rsqrtf(tot / (float)DD + 1e-6f);
  }
}

// ---------------------------------------------------------------- rmsnorm (bf16 in/out, external w)
__global__ void rmsnorm_k(const u16* __restrict__ in, const void* __restrict__ w,
                          u16* __restrict__ out, int dim, const int* fl){
  int f = *fl;
  int row = blockIdx.x;
  const u16* xp = in + (size_t)row * dim;
  float ss = 0.f;
  for (int i = threadIdx.x; i < dim; i += 256){ float v = bf2f(xp[i]); ss += v*v; }
  #pragma unroll
  for (int off = 32; off > 0; off >>= 1) ss += __shfl_down(ss, off, 64);
  __shared__ float red[4];
  __shared__ float scale_s;
  int lane = threadIdx.x & 63, wv = threadIdx.x >> 6;
  if (lane == 0) red[wv] = ss;
  __syncthreads();
  if (threadIdx.x == 0){
    float tot = red[0] + red[1] + red[2] + red[3];
    scale_s = rsqrtf(tot / (float)dim + 1e-6f);
  }
  __syncthreads();
  float sc = scale_s;
  for (int i = threadIdx.x; i < dim; i += 256)
    out[(size_t)row*dim + i] = f2bf(bf2f(xp[i]) * sc * ldany(w, i, f));
}

__global__ void rmsnorm_f32_k(const float* __restrict__ in, const void* __restrict__ w,
                              float* __restrict__ out, int dim, const int* fl){
  int f = *fl;
  int row = blockIdx.x;
  const float* xp = in + (size_t)row * dim;
  float ss = 0.f;
  for (int i = threadIdx.x; i < dim; i += 256){ float v = xp[i]; ss += v*v; }
  #pragma unroll
  for (int off = 32; off > 0; off >>= 1) ss += __shfl_down(ss, off, 64);
  __shared__ float red[4];
  __shared__ float scale_s;
  int lane = threadIdx.x & 63, wv = threadIdx.x >> 6;
  if (lane == 0) red[wv] = ss;
  __syncthreads();
  if (threadIdx.x == 0){
    float tot = red[0] + red[1] + red[2] + red[3];
    scale_s = rsqrtf(tot / (float)dim + 1e-6f);
  }
  __syncthreads();
  float sc = scale_s;
  for (int i = threadIdx.x; i < dim; i += 256)
    out[(size_t)row*dim + i] = xp[i] * sc * ldany(w, i, f);
}

// ---------------------------------------------------------------- MFMA GEMM: C = A(M,K) @ BT(N,K)^T
#define BM 128
#define BN 128
#define BK 32
#define BKP 40

typedef __attribute__((ext_vector_type(8))) __bf16 bf16x8;
typedef __attribute__((ext_vector_type(4))) float f32x4;

__device__ __forceinline__ uint4 normpack(uint4 a, float s, const float* w8){
  float v[8] = {bflo(a.x),bfhi(a.x),bflo(a.y),bfhi(a.y),
                bflo(a.z),bfhi(a.z),bflo(a.w),bfhi(a.w)};
  uint4 o;
  o.x = ((u32)f2bf(v[0]*s*w8[0])) | (((u32)f2bf(v[1]*s*w8[1])) << 16);
  o.y = ((u32)f2bf(v[2]*s*w8[2])) | (((u32)f2bf(v[3]*s*w8[3])) << 16);
  o.z = ((u32)f2bf(v[4]*s*w8[4])) | (((u32)f2bf(v[5]*s*w8[5])) << 16);
  o.w = ((u32)f2bf(v[6]*s*w8[6])) | (((u32)f2bf(v[7]*s*w8[7])) << 16);
  return o;
}

// epi: 0 = out=bf16(v+bias)
//      1 = out=silu(v+bias)
//      2 = out=silu(out)*(v+bias)      (in-place gate)
//      3 = out=bf16(bf2f(out)+v+bias)  (residual accumulate)
__global__ __launch_bounds__(256) void gemm_bt_k(
    const u16* __restrict__ A, const u16* __restrict__ BT,
    const void* __restrict__ bias, int boff,
    const float* __restrict__ ascale, const void* __restrict__ anw, int aoff,
    u16* __restrict__ out, int M, int N, int K, int epi, const int* fl)
{
  __shared__ u16 As[BM*BKP];
  __shared__ u16 Bs[BN*BKP];
  const int f = *fl;
  const int tid = threadIdx.x;
  const int wave = tid >> 6, lane = tid & 63;
  const int m0 = blockIdx.y * BM, n0 = blockIdx.x * BN;
  const int wr = (wave >> 1) * 64, wc = (wave & 1) * 64;
  const int lr = lane & 15, lq = lane >> 4;

  f32x4 acc[4][4];
  #pragma unroll
  for (int i = 0; i < 4; ++i)
    #pragma unroll
    for (int j = 0; j < 4; ++j) acc[i][j] = f32x4{0.f,0.f,0.f,0.f};

  const int rA0 = tid >> 2, rA1 = rA0 + 64;
  const int cA  = (tid & 3) * 8;
  const u16* pa0 = A + (size_t)(m0 + rA0) * K + cA;
  const u16* pa1 = A + (size_t)(m0 + rA1) * K + cA;
  const u16* pb0 = BT + (size_t)(n0 + rA0) * K + cA;
  const u16* pb1 = BT + (size_t)(n0 + rA1) * K + cA;
  float s0 = 1.f, s1 = 1.f;
  if (ascale){ s0 = ascale[m0 + rA0]; s1 = ascale[m0 + rA1]; }

  for (int kt = 0; kt < K; kt += BK){
    uint4 va0 = *(const uint4*)(pa0 + kt);
    uint4 va1 = *(const uint4*)(pa1 + kt);
    uint4 vb0 = *(const uint4*)(pb0 + kt);
    uint4 vb1 = *(const uint4*)(pb1 + kt);
    if (anw){
      float w8[8];
      #pragma unroll
      for (int j = 0; j < 8; ++j) w8[j] = ldany(anw, (size_t)(aoff + cA + kt + j), f);
      va0 = normpack(va0, s0, w8);
      va1 = normpack(va1, s1, w8);
    }
    __syncthreads();
    *(uint4*)(As + rA0 * BKP + cA) = va0;
    *(uint4*)(As + rA1 * BKP + cA) = va1;
    *(uint4*)(Bs + rA0 * BKP + cA) = vb0;
    *(uint4*)(Bs + rA1 * BKP + cA) = vb1;
    __syncthreads();
    bf16x8 af[4], bfr[4];
    #pragma unroll
    for (int i = 0; i < 4; ++i)
      af[i] = *(const bf16x8*)(As + (wr + i*16 + lr) * BKP + lq*8);
    #pragma unroll
    for (int j = 0; j < 4; ++j)
      bfr[j] = *(const bf16x8*)(Bs + (wc + j*16 + lr) * BKP + lq*8);
    #pragma unroll
    for (int i = 0; i < 4; ++i)
      #pragma unroll
      for (int j = 0; j < 4; ++j)
        acc[i][j] = __builtin_amdgcn_mfma_f32_16x16x32_bf16(af[i], bfr[j], acc[i][j], 0, 0, 0);
  }

  #pragma unroll
  for (int i = 0; i < 4; ++i){
    #pragma unroll
    for (int j = 0; j < 4; ++j){
      #pragma unroll
      for (int r = 0; r < 4; ++r){
        int row = m0 + wr + i*16 + lq*4 + r;
        int col = n0 + wc + j*16 + lr;
        size_t idx = (size_t)row * N + col;
        float v = acc[i][j][r] + ldany(bias, (size_t)(boff + col), f);
        if (epi == 0){
          out[idx] = f2bf(v);
        } else if (epi == 1){
          out[idx] = f2bf(v / (1.f + __expf(-v)));
        } else if (epi == 2){
          float g = bf2f(out[idx]);
          out[idx] = f2bf((g / (1.f + __expf(-g))) * v);
        } else {
          out[idx] = f2bf(bf2f(out[idx]) + v);
        }
      }
    }
  }
}

// ---------------------------------------------------------------- sliding attention (vector, online softmax), h bf16 +=
__global__ __launch_bounds__(256, 2) void attn_k(
    const u16* __restrict__ q, const u16* __restrict__ k,
    const u16* __restrict__ v, u16* __restrict__ h)
{
  __shared__ u16 Ks[256*64];
  __shared__ u16 Vs[256*64];
  const int c = blockIdx.x, hh = blockIdx.y, b = blockIdx.z;
  const int qi = threadIdx.x;
  const int qg = c * 256 + qi;

  float qf[64];
  {
    const uint4* qp = (const uint4*)(q + (size_t)(b*SS + qg) * DD + hh * 64);
    #pragma unroll
    for (int i = 0; i < 8; ++i){
      uint4 t = qp[i];
      qf[i*8+0] = bflo(t.x)*0.125f; qf[i*8+1] = bfhi(t.x)*0.125f;
      qf[i*8+2] = bflo(t.y)*0.125f; qf[i*8+3] = bfhi(t.y)*0.125f;
      qf[i*8+4] = bflo(t.z)*0.125f; qf[i*8+5] = bfhi(t.z)*0.125f;
      qf[i*8+6] = bflo(t.w)*0.125f; qf[i*8+7] = bfhi(t.w)*0.125f;
    }
  }
  float m = -1e30f, l = 0.f;
  float accv[64];
  #pragma unroll
  for (int d = 0; d < 64; ++d) accv[d] = 0.f;

  for (int t0 = 0; t0 < 768; t0 += 256){
    int kgbase = c*256 + t0 - 256;
    if (kgbase >= SS || kgbase + 255 < 0) continue;   // uniform per block
    {
      int kg = kgbase + qi;
      uint4* kd = (uint4*)(Ks + qi*64);
      uint4* vd = (uint4*)(Vs + qi*64);
      if (kg >= 0 && kg < SS){
        const uint4* ksrc = (const uint4*)(k + (size_t)(b*SS+kg)*DD + hh*64);
        const uint4* vsrc = (const uint4*)(v + (size_t)(b*SS+kg)*DD + hh*64);
        #pragma unroll
        for (int i = 0; i < 8; ++i){ kd[i] = ksrc[i]; vd[i] = vsrc[i]; }
      } else {
        uint4 z = {0,0,0,0};
        #pragma unroll
        for (int i = 0; i < 8; ++i){ kd[i] = z; vd[i] = z; }
      }
    }
    __syncthreads();
    for (int t = 0; t < 256; ++t){
      int pos = t0 + t;
      int kg = kgbase + t;
      bool valid = (pos >= qi) && (pos <= qi + 512) && (kg >= 0) && (kg < SS);
      if (valid){
        const uint4* kr = (const uint4*)(Ks + t*64);
        float s = 0.f;
        #pragma unroll
        for (int i = 0; i < 8; ++i){
          uint4 kv = kr[i];
          s += qf[i*8+0]*bflo(kv.x) + qf[i*8+1]*bfhi(kv.x)
             + qf[i*8+2]*bflo(kv.y) + qf[i*8+3]*bfhi(kv.y)
             + qf[i*8+4]*bflo(kv.z) + qf[i*8+5]*bfhi(kv.z)
             + qf[i*8+6]*bflo(kv.w) + qf[i*8+7]*bfhi(kv.w);
        }
        float mn = fmaxf(m, s);
        float p  = __expf(s - mn);
        float scl = __expf(m - mn);
        l = l * scl + p;
        if (scl < 1.f){
          #pragma unroll
          for (int d = 0; d < 64; ++d) accv[d] *= scl;
        }
        m = mn;
        const uint4* vr = (const uint4*)(Vs + t*64);
        #pragma unroll
        for (int i = 0; i < 8; ++i){
          uint4 vv = vr[i];
          accv[i*8+0] += p*bflo(vv.x); accv[i*8+1] += p*bfhi(vv.x);
          accv[i*8+2] += p*bflo(vv.y); accv[i*8+3] += p*bfhi(vv.y);
          accv[i*8+4] += p*bflo(vv.z); accv[i*8+5] += p*bfhi(vv.z);
          accv[i*8+6] += p*bflo(vv.w); accv[i*8+7] += p*bfhi(vv.w);
        }
      }
    }
    __syncthreads();
  }
  float inv = 1.f / l;
  u16* hp = h + (size_t)(b*SS + qg) * DD + hh*64;
  #pragma unroll
  for (int d = 0; d < 64; ++d) hp[d] = f2bf(bf2f(hp[d]) + accv[d] * inv);
}

// ---------------------------------------------------------------- small-N projection (N=4 / N=16), W external (K,N)
// outmode: 0 = always bf16 (internal); 1 = d_out dtype per flag
template<int NN>
__global__ void smalln_k(const u16* __restrict__ A, const void* __restrict__ W,
                         const void* __restrict__ bias, void* __restrict__ out,
                         int K, const int* fl, int outmode){
  int f = *fl;
  int row = blockIdx.x * blockDim.x + threadIdx.x;
  float acc[NN];
  #pragma unroll
  for (int n = 0; n < NN; ++n) acc[n] = ldany(bias, n, f);
  const uint4* a4 = (const uint4*)(A + (size_t)row * K);
  for (int k8 = 0; k8 < K/8; ++k8){
    uint4 av = a4[k8];
    float af[8] = {bflo(av.x),bfhi(av.x),bflo(av.y),bfhi(av.y),
                   bflo(av.z),bfhi(av.z),bflo(av.w),bfhi(av.w)};
    #pragma unroll
    for (int i = 0; i < 8; ++i){
      int k = k8*8 + i;
      #pragma unroll
      for (int n = 0; n < NN; ++n)
        acc[n] += af[i] * ldany(W, (size_t)k*NN + n, f);
    }
  }
  #pragma unroll
  for (int n = 0; n < NN; ++n){
    size_t oi = (size_t)row*NN + n;
    if (outmode && f) ((float*)out)[oi] = acc[n];
    else ((u16*)out)[oi] = f2bf(acc[n]);
  }
}

// ---------------------------------------------------------------- c path
__global__ void ctrans_k(const u16* __restrict__ in, u16* __restrict__ out){
  int idx = blockIdx.x * 256 + threadIdx.x;   // 2*16*4096
  int b = idx >> 16;
  int r = idx & 65535;
  int d = r >> 12, s = r & 4095;
  out[idx] = in[(size_t)(b*4096 + s)*16 + d];
}

// ct (32,4096) @ w (4096,4096 external), K-split with atomics into yacc (32,4096) f32
__global__ __launch_bounds__(256) void c2mlp1_k(const u16* __restrict__ ct,
    const void* __restrict__ w, float* __restrict__ yacc, const int* fl){
  int f = *fl;
  __shared__ float Awt[64][36];
  __shared__ u16 Ws[64*128];
  int n0 = blockIdx.x * 128;
  int k0 = blockIdx.y * 512;
  int tid = threadIdx.x;
  int c4 = (tid & 31) * 4;
  int r0 = (tid >> 5) * 4;
  float acc[4][4] = {};
  for (int ks = 0; ks < 512; ks += 64){
    __syncthreads();
    {
      int mm = tid >> 3, kk8 = (tid & 7) * 8;
      uint4 av = *(const uint4*)(ct + (size_t)mm*4096 + k0 + ks + kk8);
      float fv[8] = {bflo(av.x),bfhi(av.x),bflo(av.y),bfhi(av.y),
                     bflo(av.z),bfhi(av.z),bflo(av.w),bfhi(av.w)};
      #pragma unroll
      for (int i = 0; i < 8; ++i) Awt[kk8+i][mm] = fv[i];
    }
    {
      int kk = tid >> 2, cc = (tid & 3) * 32;
      #pragma unroll
      for (int j = 0; j < 32; ++j)
        Ws[kk*128 + cc + j] = f2bf(ldany(w, (size_t)(k0+ks+kk)*4096 + n0 + cc + j, f));
    }
    __syncthreads();
    for (int kk = 0; kk < 64; ++kk){
      float4 a4 = *(const float4*)&Awt[kk][r0];
      uint2 wv = *(const uint2*)(Ws + kk*128 + c4);
      float w0 = bflo(wv.x), w1v = bfhi(wv.x), w2v = bflo(wv.y), w3v = bfhi(wv.y);
      float ar[4] = {a4.x, a4.y, a4.z, a4.w};
      #pragma unroll
      for (int r = 0; r < 4; ++r){
        acc[r][0] += ar[r]*w0;  acc[r][1] += ar[r]*w1v;
        acc[r][2] += ar[r]*w2v; acc[r][3] += ar[r]*w3v;
      }
    }
  }
  #pragma unroll
  for (int r = 0; r < 4; ++r)
    #pragma unroll
    for (int cc = 0; cc < 4; ++cc)
      atomicAdd(&yacc[(size_t)(r0+r)*4096 + n0 + c4 + cc], acc[r][cc]);
}

__global__ void silu_bias_k(const float* __restrict__ yacc, const void* __restrict__ bias,
                            u16* __restrict__ out, const int* fl){
  int f = *fl;
  int idx = blockIdx.x*256 + threadIdx.x;    // 32*4096
  int n = idx & 4095;
  float v = yacc[idx] + ldany(bias, n, f);
  out[idx] = f2bf(v / (1.f + __expf(-v)));
}

// y (32,4096) @ w2 (4096,64 external) + b2 -> emb_pre[b*1024 + col*16 + d]
__global__ void c2mlp2_k(const u16* __restrict__ y, const void* __restrict__ w2,
                         const void* __restrict__ b2, float* __restrict__ emb_pre,
                         const int* fl){
  int f = *fl;
  int m = blockIdx.x;
  int col = threadIdx.x & 63, sl = threadIdx.x >> 6;
  float acc = 0.f;
  for (int k = sl*1024; k < (sl+1)*1024; ++k)
    acc += bf2f(y[(size_t)m*4096 + k]) * ldany(w2, (size_t)k*64 + col, f);
  __shared__ float red[256];
  red[threadIdx.x] = acc;
  __syncthreads();
  if (sl == 0){
    float t = red[col] + red[col+64] + red[col+128] + red[col+192] + ldany(b2, col, f);
    int b = m >> 4, d = m & 15;
    emb_pre[b*1024 + col*16 + d] = t;
  }
}

__global__ void head1_k(const float* __restrict__ emb, const void* __restrict__ w,
                        const void* __restrict__ bias, void* __restrict__ out,
                        const int* fl){
  int f = *fl;
  int n = blockIdx.x*256 + threadIdx.x;    // 16384
  float a0 = ldany(bias, n, f), a1 = a0;
  for (int k = 0; k < 1024; ++k){
    float wv = ldany(w, (size_t)k*16384 + n, f);
    a0 += emb[k] * wv;
    a1 += emb[1024 + k] * wv;
  }
  if (f){ ((float*)out)[32768 + n] = a0; ((float*)out)[49152 + n] = a1; }
  else  { ((u16*)out)[32768 + n] = f2bf(a0); ((u16*)out)[49152 + n] = f2bf(a1); }
}

// ================================================================ host
extern "C" void kernel_launch(void* const* d_in, const int* in_sizes, int n_in,
                              void* d_out, int out_size, void* d_ws, size_t ws_size,
                              hipStream_t stream)
{
  const int* x   = (const int*)d_in[0];
  const int* idv = (const int*)d_in[1];
  const void* embt = d_in[2];
  const void* cd_w = d_in[3];
  const void* cd_b = d_in[4];
  const void* wq = d_in[5];
  const void* bq = d_in[6];
  const void* wk = d_in[7];
  const void* bk = d_in[8];
  const void* wv = d_in[9];
  const void* bv = d_in[10];
  const void* attn_nw = d_in[11];
  const void* ffn_nw  = d_in[12];
  const void* w1 = d_in[13];
  const void* b1 = d_in[14];
  const void* w2 = d_in[15];
  const void* b2 = d_in[16];
  const void* w3 = d_in[17];
  const void* b3 = d_in[18];
  const void* h0_w1 = d_in[19];
  const void* h0_b1 = d_in[20];
  const void* h0_w2 = d_in[21];
  const void* h0_b2 = d_in[22];
  const void* nh0_w = d_in[23];
  const void* head0_w = d_in[24];
  const void* head0_b = d_in[25];
  const void* c1_w1 = d_in[26];
  const void* c1_b1 = d_in[27];
  const void* c1_w2 = d_in[28];
  const void* c1_b2 = d_in[29];
  const void* c2_w1 = d_in[30];
  const void* c2_b1 = d_in[31];
  const void* c2_w2 = d_in[32];
  const void* c2_b2 = d_in[33];
  const void* nemb_w = d_in[34];
  const void* head1_w = d_in[35];
  const void* head1_b = d_in[36];

  char* ws = (char*)d_ws;
  size_t off = 0;
  auto alloc = [&](size_t bytes)->char*{
    char* p = ws + off; off = (off + bytes + 255) & ~(size_t)255; return p;
  };

  int*  flag  = (int*)alloc(256);
  u16*  wtbuf = (u16*)alloc((size_t)2048*768*2);        // rotating transposed-weight buffer (bf16)
  u16*  h     = (u16*)alloc((size_t)NROWS*768*2);       // residual stream bf16
  float* rs   = (float*)alloc((size_t)NROWS*4);         // per-row rms scales
  char* R3    = alloc((size_t)NROWS*768*2*3);           // 37.75MB union scratch

  u16* xin  = (u16*)R3;                                  // (8192,288)
  u16* qb   = (u16*)R3;
  u16* kb   = (u16*)(R3 + (size_t)NROWS*768*2);
  u16* vb   = (u16*)(R3 + (size_t)NROWS*768*2*2);
  u16* g1   = (u16*)R3;                                  // (8192,2048)
  u16* tbuf = (u16*)R3;                                  // (8192,768)
  u16* gbuf = (u16*)(R3 + (size_t)NROWS*768*2);          // (8192,768)
  char* tail = R3 + (size_t)NROWS*768*2*2;
  u16* cbuf = (u16*)tail;                                // (8192,16)
  u16* ctb  = (u16*)(tail + 262144);                     // (32,4096)
  float* yacc = (float*)(tail + 262144*2);               // (32,4096) f32
  u16* ybf  = (u16*)(tail + 262144*2 + 524288);          // (32,4096)
  float* emb_pre = (float*)(tail + 262144*3 + 524288);   // (2,1024) f32
  float* embn    = (float*)(tail + 262144*3 + 524288 + 8192);

  detect_k<<<1, 64, 0, stream>>>(attn_nw, flag);

  auto tr = [&](const void* src, size_t ioff, int R, int C){  // src (R,C) -> wtbuf (C,R) bf16
    dim3 g((C+31)/32, (R+31)/32);
    transpose_k<<<g, 256, 0, stream>>>(src, ioff, wtbuf, R, C, flag);
  };
  auto gemm = [&](const u16* A, const void* bias, int boff,
                  const float* ascale, const void* anw, int aoff,
                  u16* out_, int M, int N, int K, int epi){
    dim3 g(N/128, M/128);
    gemm_bt_k<<<g, 256, 0, stream>>>(A, wtbuf, bias, boff, ascale, anw, aoff,
                                     out_, M, N, K, epi, flag);
  };

  // embed + concat-id -> xin;  h = xin @ cd_w + cd_b
  embed_k<<<NROWS, 256, 0, stream>>>(x, idv, embt, xin, flag);
  tr(cd_w, 0, 288, 768);
  gemm(xin, cd_b, 0, nullptr, nullptr, 0, h, NROWS, 768, 288, 0);

  for (int l = 0; l < 4; ++l){
    size_t wo = (size_t)l*768*768, fo = (size_t)l*768*2048;
    rowscale_k<<<NROWS, 256, 0, stream>>>(h, rs);
    tr(wq, wo, 768, 768);
    gemm(h, bq, l*768, rs, attn_nw, l*768, qb, NROWS, 768, 768, 0);
    tr(wk, wo, 768, 768);
    gemm(h, bk, l*768, rs, attn_nw, l*768, kb, NROWS, 768, 768, 0);
    tr(wv, wo, 768, 768);
    gemm(h, bv, l*768, rs, attn_nw, l*768, vb, NROWS, 768, 768, 0);
    attn_k<<<dim3(16,12,2), 256, 0, stream>>>(qb, kb, vb, h);

    rowscale_k<<<NROWS, 256, 0, stream>>>(h, rs);
    tr(w1, fo, 768, 2048);
    gemm(h, b1, l*2048, rs, ffn_nw, l*768, g1, NROWS, 2048, 768, 0);
    tr(w3, fo, 768, 2048);
    gemm(h, b3, l*2048, rs, ffn_nw, l*768, g1, NROWS, 2048, 768, 2);  // in-place gate
    tr(w2, fo, 2048, 768);
    gemm(g1, b2, l*768, nullptr, nullptr, 0, h, NROWS, 768, 2048, 3); // residual
  }

  // head0 path
  tr(h0_w1, 0, 768, 768);
  gemm(h, h0_b1, 0, nullptr, nullptr, 0, gbuf, NROWS, 768, 768, 1);
  tr(h0_w2, 0, 768, 768);
  gemm(gbuf, h0_b2, 0, nullptr, nullptr, 0, tbuf, NROWS, 768, 768, 0);
  rmsnorm_k<<<NROWS, 256, 0, stream>>>(tbuf, nh0_w, gbuf, 768, flag);
  smalln_k<4><<<NROWS/256, 256, 0, stream>>>(gbuf, head0_w, head0_b, d_out, 768, flag, 1);

  // c path
  tr(c1_w1, 0, 768, 768);
  gemm(h, c1_b1, 0, nullptr, nullptr, 0, gbuf, NROWS, 768, 768, 1);
  smalln_k<16><<<NROWS/256, 256, 0, stream>>>(gbuf, c1_w2, c1_b2, cbuf, 768, flag, 0);
  ctrans_k<<<512, 256, 0, stream>>>(cbuf, ctb);
  hipMemsetAsync(yacc, 0, (size_t)32*4096*4, stream);
  c2mlp1_k<<<dim3(32,8), 256, 0, stream>>>(ctb, c2_w1, yacc, flag);
  silu_bias_k<<<512, 256, 0, stream>>>(yacc, c2_b1, ybf, flag);
  c2mlp2_k<<<32, 256, 0, stream>>>(ybf, c2_w2, c2_b2, emb_pre, flag);
  rmsnorm_f32_k<<<2, 256, 0, stream>>>(emb_pre, nemb_w, embn, 1024, flag);
  head1_k<<<64, 256, 0, stream>>>(embn, head1_w, head1_b, d_out, flag);

  (void)in_sizes; (void)n_in; (void)out_size; (void)ws_size;
}

// Round 4
// 5223.292 us; speedup vs baseline: 1.2860x; 1.2860x over previous
//
#include <hip/hip_runtime.h>
#include <stdint.h>

typedef unsigned short u16;
typedef unsigned int u32;

#define SS 4096
#define NROWS 8192   // B*S

__device__ __forceinline__ float bf2f(u16 u){
  union { u32 u; float f; } x; x.u = ((u32)u) << 16; return x.f;
}
__device__ __forceinline__ u16 f2bf(float f){
  union { float f; u32 u; } x; x.f = f;
  u32 r = x.u + 0x7fffu + ((x.u >> 16) & 1u);
  return (u16)(r >> 16);
}
__device__ __forceinline__ float bflo(u32 u){ union { u32 u; float f; } x; x.u = u << 16; return x.f; }
__device__ __forceinline__ float bfhi(u32 u){ union { u32 u; float f; } x; x.u = u & 0xffff0000u; return x.f; }

// flag==1: external float tensors are fp32; flag==0: bf16
__device__ __forceinline__ float ldany(const void* p, size_t i, int f){
  return f ? ((const float*)p)[i] : bf2f(((const u16*)p)[i]);
}

__global__ void detect_k(const void* anw, int* flag){
  if (threadIdx.x == 0 && blockIdx.x == 0)
    flag[0] = (((const u32*)anw)[0] == 0x3F800000u) ? 1 : 0;
}

// ---------------------------------------------------------------- transpose (any-float in -> bf16 out)
__global__ void transpose_k(const void* __restrict__ in, size_t ioff,
                            u16* __restrict__ out, int R, int C, const int* fl){
  int f = *fl;
  __shared__ u16 t[32][33];
  int c0 = blockIdx.x * 32, r0 = blockIdx.y * 32;
  int tx = threadIdx.x & 31, ty = threadIdx.x >> 5; // 32x8
  #pragma unroll
  for (int i = 0; i < 32; i += 8){
    int r = r0 + ty + i, c = c0 + tx;
    t[ty + i][tx] = (r < R && c < C) ? f2bf(ldany(in, ioff + (size_t)r * C + c, f)) : (u16)0;
  }
  __syncthreads();
  #pragma unroll
  for (int i = 0; i < 32; i += 8){
    int r = c0 + ty + i, c = r0 + tx;
    if (r < C && c < R) out[(size_t)r * R + c] = t[tx][ty + i];
  }
}

// ---------------------------------------------------------------- embed + id bits
__global__ void embed_k(const int* __restrict__ x, const int* __restrict__ idv,
                        const void* __restrict__ table, u16* __restrict__ xin,
                        const int* fl){
  int f = *fl;
  int row = blockIdx.x;
  int tok = x[row], idval = idv[row];
  for (int j = threadIdx.x; j < 288; j += 256){
    u16 o;
    if (j < 256) o = f2bf(ldany(table, (size_t)tok*256 + j, f) * 16.0f);   // * sqrt(DV)
    else o = ((idval >> (31 - (j - 256))) & 1) ? (u16)0x3F80 : (u16)0;
    xin[(size_t)row * 288 + j] = o;
  }
}

// ---------------------------------------------------------------- per-row rms scale (wave per row, 4 rows/block)
__global__ __launch_bounds__(256) void rowscale_k(const u16* __restrict__ h, float* __restrict__ s){
  int wave = threadIdx.x >> 6, lane = threadIdx.x & 63;
  int row = blockIdx.x*4 + wave;
  const u16* xp = h + (size_t)row * 768;
  float ss = 0.f;
  #pragma unroll
  for (int i = 0; i < 12; ++i){ float v = bf2f(xp[i*64 + lane]); ss += v*v; }
  #pragma unroll
  for (int o = 32; o > 0; o >>= 1) ss += __shfl_down(ss, o, 64);
  if (lane == 0) s[row] = rsqrtf(ss / 768.f + 1e-6f);
}

// ---------------------------------------------------------------- rmsnorm bf16->bf16 (wave per row)
__global__ __launch_bounds__(256) void rmsnorm_k(const u16* __restrict__ in, const void* __restrict__ w,
                          u16* __restrict__ out, const int* fl){
  int f = *fl;
  int wave = threadIdx.x >> 6, lane = threadIdx.x & 63;
  int row = blockIdx.x*4 + wave;
  const u16* xp = in + (size_t)row * 768;
  float v[12]; float ss = 0.f;
  #pragma unroll
  for (int i = 0; i < 12; ++i){ v[i] = bf2f(xp[i*64 + lane]); ss += v[i]*v[i]; }
  #pragma unroll
  for (int o = 32; o > 0; o >>= 1) ss += __shfl_down(ss, o, 64);
  float tot = __shfl(ss, 0, 64);
  float sc = rsqrtf(tot / 768.f + 1e-6f);
  u16* op = out + (size_t)row * 768;
  #pragma unroll
  for (int i = 0; i < 12; ++i)
    op[i*64 + lane] = f2bf(v[i] * sc * ldany(w, i*64 + lane, f));
}

// emb rmsnorm with fused col-bias (2 rows of 1024; bias b2 indexed i>>4)
__global__ void rmsnorm_emb_k(const float* __restrict__ in, const void* __restrict__ b2,
                              const void* __restrict__ w, float* __restrict__ out, const int* fl){
  int f = *fl;
  int row = blockIdx.x;
  const float* xp = in + (size_t)row * 1024;
  float ss = 0.f;
  for (int i = threadIdx.x; i < 1024; i += 256){
    float v = xp[i] + ldany(b2, i >> 4, f); ss += v*v;
  }
  #pragma unroll
  for (int o = 32; o > 0; o >>= 1) ss += __shfl_down(ss, o, 64);
  __shared__ float red[4];
  __shared__ float scale_s;
  int lane = threadIdx.x & 63, wv = threadIdx.x >> 6;
  if (lane == 0) red[wv] = ss;
  __syncthreads();
  if (threadIdx.x == 0){
    float tot = red[0] + red[1] + red[2] + red[3];
    scale_s = rsqrtf(tot / 1024.f + 1e-6f);
  }
  __syncthreads();
  float sc = scale_s;
  for (int i = threadIdx.x; i < 1024; i += 256)
    out[(size_t)row*1024 + i] = (xp[i] + ldany(b2, i >> 4, f)) * sc * ldany(w, i, f);
}

// ---------------------------------------------------------------- MFMA GEMM: C = A(M,K) @ BT(N,K)^T
#define BM 128
#define BN 128
#define BK 32
#define BKP 40

typedef __attribute__((ext_vector_type(8))) __bf16 bf16x8;
typedef __attribute__((ext_vector_type(4))) float f32x4;

__device__ __forceinline__ uint4 normpack(uint4 a, float s, const float* w8){
  float v[8] = {bflo(a.x),bfhi(a.x),bflo(a.y),bfhi(a.y),
                bflo(a.z),bfhi(a.z),bflo(a.w),bfhi(a.w)};
  uint4 o;
  o.x = ((u32)f2bf(v[0]*s*w8[0])) | (((u32)f2bf(v[1]*s*w8[1])) << 16);
  o.y = ((u32)f2bf(v[2]*s*w8[2])) | (((u32)f2bf(v[3]*s*w8[3])) << 16);
  o.z = ((u32)f2bf(v[4]*s*w8[4])) | (((u32)f2bf(v[5]*s*w8[5])) << 16);
  o.w = ((u32)f2bf(v[6]*s*w8[6])) | (((u32)f2bf(v[7]*s*w8[7])) << 16);
  return o;
}

// epi: 0 = out=bf16(v+bias); 1 = silu; 2 = out=silu(out)*(v+bias); 3 = out += v+bias
__global__ __launch_bounds__(256) void gemm_bt_k(
    const u16* __restrict__ A, const u16* __restrict__ BT,
    const void* __restrict__ bias, const void* __restrict__ bias2,
    const void* __restrict__ bias3, int boff,
    const float* __restrict__ ascale, const void* __restrict__ anw, int aoff,
    u16* __restrict__ out, int M, int N, int K, int epi, const int* fl)
{
  __shared__ u16 As[BM*BKP];
  __shared__ u16 Bs[BN*BKP];
  const int f = *fl;
  const int tid = threadIdx.x;
  const int wave = tid >> 6, lane = tid & 63;
  const int m0 = blockIdx.y * BM, n0 = blockIdx.x * BN;
  const int wr = (wave >> 1) * 64, wc = (wave & 1) * 64;
  const int lr = lane & 15, lq = lane >> 4;

  f32x4 acc[4][4];
  #pragma unroll
  for (int i = 0; i < 4; ++i)
    #pragma unroll
    for (int j = 0; j < 4; ++j) acc[i][j] = f32x4{0.f,0.f,0.f,0.f};

  const int rA0 = tid >> 2, rA1 = rA0 + 64;
  const int cA  = (tid & 3) * 8;
  const u16* pa0 = A + (size_t)(m0 + rA0) * K + cA;
  const u16* pa1 = A + (size_t)(m0 + rA1) * K + cA;
  const u16* pb0 = BT + (size_t)(n0 + rA0) * K + cA;
  const u16* pb1 = BT + (size_t)(n0 + rA1) * K + cA;
  float s0 = 1.f, s1 = 1.f;
  if (ascale){ s0 = ascale[m0 + rA0]; s1 = ascale[m0 + rA1]; }

  for (int kt = 0; kt < K; kt += BK){
    uint4 va0 = *(const uint4*)(pa0 + kt);
    uint4 va1 = *(const uint4*)(pa1 + kt);
    uint4 vb0 = *(const uint4*)(pb0 + kt);
    uint4 vb1 = *(const uint4*)(pb1 + kt);
    if (anw){
      float w8[8];
      #pragma unroll
      for (int j = 0; j < 8; ++j) w8[j] = ldany(anw, (size_t)(aoff + cA + kt + j), f);
      va0 = normpack(va0, s0, w8);
      va1 = normpack(va1, s1, w8);
    }
    __syncthreads();
    *(uint4*)(As + rA0 * BKP + cA) = va0;
    *(uint4*)(As + rA1 * BKP + cA) = va1;
    *(uint4*)(Bs + rA0 * BKP + cA) = vb0;
    *(uint4*)(Bs + rA1 * BKP + cA) = vb1;
    __syncthreads();
    bf16x8 af[4], bfr[4];
    #pragma unroll
    for (int i = 0; i < 4; ++i)
      af[i] = *(const bf16x8*)(As + (wr + i*16 + lr) * BKP + lq*8);
    #pragma unroll
    for (int j = 0; j < 4; ++j)
      bfr[j] = *(const bf16x8*)(Bs + (wc + j*16 + lr) * BKP + lq*8);
    #pragma unroll
    for (int i = 0; i < 4; ++i)
      #pragma unroll
      for (int j = 0; j < 4; ++j)
        acc[i][j] = __builtin_amdgcn_mfma_f32_16x16x32_bf16(af[i], bfr[j], acc[i][j], 0, 0, 0);
  }

  #pragma unroll
  for (int i = 0; i < 4; ++i){
    #pragma unroll
    for (int j = 0; j < 4; ++j){
      #pragma unroll
      for (int r = 0; r < 4; ++r){
        int row = m0 + wr + i*16 + lq*4 + r;
        int col = n0 + wc + j*16 + lr;
        size_t idx = (size_t)row * N + col;
        float bb;
        if (bias3){
          if (col < 768) bb = ldany(bias, boff + col, f);
          else if (col < 1536) bb = ldany(bias2, boff + col - 768, f);
          else bb = ldany(bias3, boff + col - 1536, f);
        } else {
          bb = ldany(bias, boff + col, f);
        }
        float v = acc[i][j][r] + bb;
        if (epi == 0){
          out[idx] = f2bf(v);
        } else if (epi == 1){
          out[idx] = f2bf(v / (1.f + __expf(-v)));
        } else if (epi == 2){
          float g = bf2f(out[idx]);
          out[idx] = f2bf((g / (1.f + __expf(-g))) * v);
        } else {
          out[idx] = f2bf(bf2f(out[idx]) + v);
        }
      }
    }
  }
}

// ---------------------------------------------------------------- sliding attention on fused QKV (stride 2304)
__global__ __launch_bounds__(256, 2) void attn_k(
    const u16* __restrict__ qkv, u16* __restrict__ h)
{
  __shared__ u16 Ks[256*64];
  __shared__ u16 Vs[256*64];
  const int c = blockIdx.x, hh = blockIdx.y, b = blockIdx.z;
  const int qi = threadIdx.x;
  const int qg = c * 256 + qi;

  float qf[64];
  {
    const uint4* qp = (const uint4*)(qkv + (size_t)(b*SS + qg) * 2304 + hh * 64);
    #pragma unroll
    for (int i = 0; i < 8; ++i){
      uint4 t = qp[i];
      qf[i*8+0] = bflo(t.x)*0.125f; qf[i*8+1] = bfhi(t.x)*0.125f;
      qf[i*8+2] = bflo(t.y)*0.125f; qf[i*8+3] = bfhi(t.y)*0.125f;
      qf[i*8+4] = bflo(t.z)*0.125f; qf[i*8+5] = bfhi(t.z)*0.125f;
      qf[i*8+6] = bflo(t.w)*0.125f; qf[i*8+7] = bfhi(t.w)*0.125f;
    }
  }
  float m = -1e30f, l = 0.f;
  float accv[64];
  #pragma unroll
  for (int d = 0; d < 64; ++d) accv[d] = 0.f;

  for (int t0 = 0; t0 < 768; t0 += 256){
    int kgbase = c*256 + t0 - 256;
    if (kgbase >= SS || kgbase + 255 < 0) continue;   // uniform per block
    {
      int kg = kgbase + qi;
      uint4* kd = (uint4*)(Ks + qi*64);
      uint4* vd = (uint4*)(Vs + qi*64);
      if (kg >= 0 && kg < SS){
        const uint4* ksrc = (const uint4*)(qkv + (size_t)(b*SS+kg)*2304 + 768 + hh*64);
        const uint4* vsrc = (const uint4*)(qkv + (size_t)(b*SS+kg)*2304 + 1536 + hh*64);
        #pragma unroll
        for (int i = 0; i < 8; ++i){ kd[i] = ksrc[i]; vd[i] = vsrc[i]; }
      } else {
        uint4 z = {0,0,0,0};
        #pragma unroll
        for (int i = 0; i < 8; ++i){ kd[i] = z; vd[i] = z; }
      }
    }
    __syncthreads();
    for (int t = 0; t < 256; ++t){
      int pos = t0 + t;
      int kg = kgbase + t;
      bool valid = (pos >= qi) && (pos <= qi + 512) && (kg >= 0) && (kg < SS);
      if (valid){
        const uint4* kr = (const uint4*)(Ks + t*64);
        float s = 0.f;
        #pragma unroll
        for (int i = 0; i < 8; ++i){
          uint4 kv = kr[i];
          s += qf[i*8+0]*bflo(kv.x) + qf[i*8+1]*bfhi(kv.x)
             + qf[i*8+2]*bflo(kv.y) + qf[i*8+3]*bfhi(kv.y)
             + qf[i*8+4]*bflo(kv.z) + qf[i*8+5]*bfhi(kv.z)
             + qf[i*8+6]*bflo(kv.w) + qf[i*8+7]*bfhi(kv.w);
        }
        float mn = fmaxf(m, s);
        float p  = __expf(s - mn);
        float scl = __expf(m - mn);
        l = l * scl + p;
        if (scl < 1.f){
          #pragma unroll
          for (int d = 0; d < 64; ++d) accv[d] *= scl;
        }
        m = mn;
        const uint4* vr = (const uint4*)(Vs + t*64);
        #pragma unroll
        for (int i = 0; i < 8; ++i){
          uint4 vv = vr[i];
          accv[i*8+0] += p*bflo(vv.x); accv[i*8+1] += p*bfhi(vv.x);
          accv[i*8+2] += p*bflo(vv.y); accv[i*8+3] += p*bfhi(vv.y);
          accv[i*8+4] += p*bflo(vv.z); accv[i*8+5] += p*bfhi(vv.z);
          accv[i*8+6] += p*bflo(vv.w); accv[i*8+7] += p*bfhi(vv.w);
        }
      }
    }
    __syncthreads();
  }
  float inv = 1.f / l;
  u16* hp = h + (size_t)(b*SS + qg) * 768 + hh*64;
  #pragma unroll
  for (int d = 0; d < 64; ++d) hp[d] = f2bf(bf2f(hp[d]) + accv[d] * inv);
}

// ---------------------------------------------------------------- small-N projection v2 (wave/row, LDS W)
// K fixed = 768. Block: 256 thr = 4 waves, 4 rows each -> 16 rows/block, grid 512.
template<int NN>
__global__ __launch_bounds__(256) void smalln_k(const u16* __restrict__ A, const void* __restrict__ W,
                         const void* __restrict__ bias, void* __restrict__ out,
                         const int* fl, int outmode){
  int f = *fl;
  __shared__ float Wl[NN*768];
  for (int i = threadIdx.x; i < NN*768; i += 256){
    int n = i / 768, k = i - n*768;
    Wl[i] = ldany(W, (size_t)k*NN + n, f);
  }
  __syncthreads();
  int wave = threadIdx.x >> 6, lane = threadIdx.x & 63;
  int rowbase = blockIdx.x*16 + wave*4;
  for (int r = 0; r < 4; ++r){
    int row = rowbase + r;
    const u16* ap = A + (size_t)row * 768;
    float a[12];
    #pragma unroll
    for (int i = 0; i < 12; ++i) a[i] = bf2f(ap[i*64 + lane]);
    float acc[NN];
    #pragma unroll
    for (int n = 0; n < NN; ++n) acc[n] = 0.f;
    #pragma unroll
    for (int i = 0; i < 12; ++i){
      int k = i*64 + lane;
      #pragma unroll
      for (int n = 0; n < NN; ++n) acc[n] += a[i] * Wl[n*768 + k];
    }
    float red[NN];
    #pragma unroll
    for (int n = 0; n < NN; ++n){
      float v = acc[n];
      #pragma unroll
      for (int o = 32; o > 0; o >>= 1) v += __shfl_down(v, o, 64);
      red[n] = v;
    }
    if (lane == 0){
      #pragma unroll
      for (int n = 0; n < NN; ++n){
        float v = red[n] + ldany(bias, n, f);
        size_t oi = (size_t)row*NN + n;
        if (outmode && f) ((float*)out)[oi] = v;
        else ((u16*)out)[oi] = f2bf(v);
      }
    }
  }
}

// ---------------------------------------------------------------- c path
__global__ void ctrans_k(const u16* __restrict__ in, u16* __restrict__ out){
  int idx = blockIdx.x * 256 + threadIdx.x;   // 2*16*4096
  int b = idx >> 16;
  int r = idx & 65535;
  int d = r >> 12, s = r & 4095;
  out[idx] = in[(size_t)(b*4096 + s)*16 + d];
}

// ct (32,4096) @ w (4096,4096 external), K-split atomics into yacc (32,4096) f32
__global__ __launch_bounds__(256) void c2mlp1_k(const u16* __restrict__ ct,
    const void* __restrict__ w, float* __restrict__ yacc, const int* fl){
  int f = *fl;
  __shared__ float Awt[64][36];
  __shared__ u16 Ws[64*128];
  int n0 = blockIdx.x * 128;
  int k0 = blockIdx.y * 512;
  int tid = threadIdx.x;
  int c4 = (tid & 31) * 4;
  int r0 = (tid >> 5) * 4;
  float acc[4][4] = {};
  for (int ks = 0; ks < 512; ks += 64){
    __syncthreads();
    {
      int mm = tid >> 3, kk8 = (tid & 7) * 8;
      uint4 av = *(const uint4*)(ct + (size_t)mm*4096 + k0 + ks + kk8);
      float fv[8] = {bflo(av.x),bfhi(av.x),bflo(av.y),bfhi(av.y),
                     bflo(av.z),bfhi(av.z),bflo(av.w),bfhi(av.w)};
      #pragma unroll
      for (int i = 0; i < 8; ++i) Awt[kk8+i][mm] = fv[i];
    }
    {
      int kk = tid >> 2, cc = (tid & 3) * 32;
      #pragma unroll
      for (int j = 0; j < 32; ++j)
        Ws[kk*128 + cc + j] = f2bf(ldany(w, (size_t)(k0+ks+kk)*4096 + n0 + cc + j, f));
    }
    __syncthreads();
    for (int kk = 0; kk < 64; ++kk){
      float4 a4 = *(const float4*)&Awt[kk][r0];
      uint2 wv = *(const uint2*)(Ws + kk*128 + c4);
      float w0 = bflo(wv.x), w1v = bfhi(wv.x), w2v = bflo(wv.y), w3v = bfhi(wv.y);
      float ar[4] = {a4.x, a4.y, a4.z, a4.w};
      #pragma unroll
      for (int r = 0; r < 4; ++r){
        acc[r][0] += ar[r]*w0;  acc[r][1] += ar[r]*w1v;
        acc[r][2] += ar[r]*w2v; acc[r][3] += ar[r]*w3v;
      }
    }
  }
  #pragma unroll
  for (int r = 0; r < 4; ++r)
    #pragma unroll
    for (int cc = 0; cc < 4; ++cc)
      atomicAdd(&yacc[(size_t)(r0+r)*4096 + n0 + c4 + cc], acc[r][cc]);
}

__global__ void silu_bias_k(const float* __restrict__ yacc, const void* __restrict__ bias,
                            u16* __restrict__ out, const int* fl){
  int f = *fl;
  int idx = blockIdx.x*256 + threadIdx.x;    // 32*4096
  int n = idx & 4095;
  float v = yacc[idx] + ldany(bias, n, f);
  out[idx] = f2bf(v / (1.f + __expf(-v)));
}

// y (32,4096) @ w2 (4096,64), K-split atomics into emb_pre (bias added in rmsnorm_emb)
__global__ void c2mlp2_k(const u16* __restrict__ y, const void* __restrict__ w2,
                         float* __restrict__ emb_pre, const int* fl){
  int f = *fl;
  int m = blockIdx.x, kseg = blockIdx.y;
  int col = threadIdx.x & 63, sl = threadIdx.x >> 6;
  float acc = 0.f;
  int kb = kseg*512 + sl*128;
  for (int k = kb; k < kb+128; ++k)
    acc += bf2f(y[(size_t)m*4096 + k]) * ldany(w2, (size_t)k*64 + col, f);
  __shared__ float red[256];
  red[threadIdx.x] = acc;
  __syncthreads();
  if (sl == 0){
    float t = red[col] + red[col+64] + red[col+128] + red[col+192];
    int b = m >> 4, d = m & 15;
    atomicAdd(&emb_pre[b*1024 + col*16 + d], t);
  }
}

// head1: K-split atomics into hacc, then finish with bias
__global__ void head1_k(const float* __restrict__ emb, const void* __restrict__ w,
                        float* __restrict__ hacc, const int* fl){
  int f = *fl;
  int n = blockIdx.x*256 + threadIdx.x;    // 16384
  int k0 = blockIdx.y*256;
  float a0 = 0.f, a1 = 0.f;
  for (int k = k0; k < k0+256; ++k){
    float wv = ldany(w, (size_t)k*16384 + n, f);
    a0 += emb[k] * wv;
    a1 += emb[1024 + k] * wv;
  }
  atomicAdd(&hacc[n], a0);
  atomicAdd(&hacc[16384 + n], a1);
}

__global__ void head1fin_k(const float* __restrict__ hacc, const void* __restrict__ bias,
                           void* __restrict__ out, const int* fl){
  int f = *fl;
  int n = blockIdx.x*256 + threadIdx.x;
  float b = ldany(bias, n, f);
  float a0 = hacc[n] + b, a1 = hacc[16384 + n] + b;
  if (f){ ((float*)out)[32768 + n] = a0; ((float*)out)[49152 + n] = a1; }
  else  { ((u16*)out)[32768 + n] = f2bf(a0); ((u16*)out)[49152 + n] = f2bf(a1); }
}

// ================================================================ host
extern "C" void kernel_launch(void* const* d_in, const int* in_sizes, int n_in,
                              void* d_out, int out_size, void* d_ws, size_t ws_size,
                              hipStream_t stream)
{
  const int* x   = (const int*)d_in[0];
  const int* idv = (const int*)d_in[1];
  const void* embt = d_in[2];
  const void* cd_w = d_in[3];
  const void* cd_b = d_in[4];
  const void* wq = d_in[5];
  const void* bq = d_in[6];
  const void* wk = d_in[7];
  const void* bk = d_in[8];
  const void* wv = d_in[9];
  const void* bv = d_in[10];
  const void* attn_nw = d_in[11];
  const void* ffn_nw  = d_in[12];
  const void* w1 = d_in[13];
  const void* b1 = d_in[14];
  const void* w2 = d_in[15];
  const void* b2 = d_in[16];
  const void* w3 = d_in[17];
  const void* b3 = d_in[18];
  const void* h0_w1 = d_in[19];
  const void* h0_b1 = d_in[20];
  const void* h0_w2 = d_in[21];
  const void* h0_b2 = d_in[22];
  const void* nh0_w = d_in[23];
  const void* head0_w = d_in[24];
  const void* head0_b = d_in[25];
  const void* c1_w1 = d_in[26];
  const void* c1_b1 = d_in[27];
  const void* c1_w2 = d_in[28];
  const void* c1_b2 = d_in[29];
  const void* c2_w1 = d_in[30];
  const void* c2_b1 = d_in[31];
  const void* c2_w2 = d_in[32];
  const void* c2_b2 = d_in[33];
  const void* nemb_w = d_in[34];
  const void* head1_w = d_in[35];
  const void* head1_b = d_in[36];

  char* ws = (char*)d_ws;
  size_t off = 0;
  auto alloc = [&](size_t bytes)->char*{
    char* p = ws + off; off = (off + bytes + 255) & ~(size_t)255; return p;
  };

  int*  flag  = (int*)alloc(256);
  u16*  wtbuf = (u16*)alloc((size_t)2304*768*2);        // rotating transposed-weight buffer (bf16)
  u16*  h     = (u16*)alloc((size_t)NROWS*768*2);       // residual stream bf16
  float* rs   = (float*)alloc((size_t)NROWS*4);         // per-row rms scales
  char* R3    = alloc((size_t)NROWS*768*2*3);           // 37.75MB union scratch

  u16* xin  = (u16*)R3;                                  // (8192,288)
  u16* qkvb = (u16*)R3;                                  // (8192,2304) fused QKV
  u16* g1   = (u16*)R3;                                  // (8192,2048)
  u16* tbuf = (u16*)R3;                                  // (8192,768)
  u16* gbuf = (u16*)(R3 + (size_t)NROWS*768*2);          // (8192,768)
  char* tail = R3 + (size_t)NROWS*768*2*2;
  u16* cbuf = (u16*)tail;                                // (8192,16)
  u16* ctb  = (u16*)(tail + 262144);                     // (32,4096)
  float* yacc = (float*)(tail + 262144*2);               // (32,4096) f32
  u16* ybf  = (u16*)(tail + 262144*2 + 524288);          // (32,4096)
  float* emb_pre = (float*)(tail + 262144*3 + 524288);   // (2,1024) f32
  float* embn    = (float*)(tail + 262144*3 + 524288 + 8192);
  float* hacc    = (float*)(tail + 262144*3 + 524288 + 16384); // (2,16384) f32

  detect_k<<<1, 64, 0, stream>>>(attn_nw, flag);

  auto tr = [&](const void* src, size_t ioff, u16* dst, int R, int C){
    dim3 g((C+31)/32, (R+31)/32);
    transpose_k<<<g, 256, 0, stream>>>(src, ioff, dst, R, C, flag);
  };
  auto gemm = [&](const u16* A, const void* bias, int boff,
                  const float* ascale, const void* anw, int aoff,
                  u16* out_, int M, int N, int K, int epi){
    dim3 g(N/128, M/128);
    gemm_bt_k<<<g, 256, 0, stream>>>(A, wtbuf, bias, nullptr, nullptr, boff,
                                     ascale, anw, aoff, out_, M, N, K, epi, flag);
  };

  // embed + concat-id -> xin;  h = xin @ cd_w + cd_b
  embed_k<<<NROWS, 256, 0, stream>>>(x, idv, embt, xin, flag);
  tr(cd_w, 0, wtbuf, 288, 768);
  gemm(xin, cd_b, 0, nullptr, nullptr, 0, h, NROWS, 768, 288, 0);

  for (int l = 0; l < 4; ++l){
    size_t wo = (size_t)l*768*768, fo = (size_t)l*768*2048;
    rowscale_k<<<NROWS/4, 256, 0, stream>>>(h, rs);
    // fused QKV: wtbuf rows [0,768)=wq^T, [768,1536)=wk^T, [1536,2304)=wv^T
    tr(wq, wo, wtbuf,              768, 768);
    tr(wk, wo, wtbuf + 768*768,    768, 768);
    tr(wv, wo, wtbuf + 2*768*768,  768, 768);
    {
      dim3 g(2304/128, NROWS/128);
      gemm_bt_k<<<g, 256, 0, stream>>>(h, wtbuf, bq, bk, bv, l*768,
                                       rs, attn_nw, l*768, qkvb, NROWS, 2304, 768, 0, flag);
    }
    attn_k<<<dim3(16,12,2), 256, 0, stream>>>(qkvb, h);

    rowscale_k<<<NROWS/4, 256, 0, stream>>>(h, rs);
    tr(w1, fo, wtbuf, 768, 2048);
    gemm(h, b1, l*2048, rs, ffn_nw, l*768, g1, NROWS, 2048, 768, 0);
    tr(w3, fo, wtbuf, 768, 2048);
    gemm(h, b3, l*2048, rs, ffn_nw, l*768, g1, NROWS, 2048, 768, 2);  // in-place gate
    tr(w2, fo, wtbuf, 2048, 768);
    gemm(g1, b2, l*768, nullptr, nullptr, 0, h, NROWS, 768, 2048, 3); // residual
  }

  // head0 path
  tr(h0_w1, 0, wtbuf, 768, 768);
  gemm(h, h0_b1, 0, nullptr, nullptr, 0, gbuf, NROWS, 768, 768, 1);
  tr(h0_w2, 0, wtbuf, 768, 768);
  gemm(gbuf, h0_b2, 0, nullptr, nullptr, 0, tbuf, NROWS, 768, 768, 0);
  rmsnorm_k<<<NROWS/4, 256, 0, stream>>>(tbuf, nh0_w, gbuf, flag);
  smalln_k<4><<<NROWS/16, 256, 0, stream>>>(gbuf, head0_w, head0_b, d_out, flag, 1);

  // c path
  tr(c1_w1, 0, wtbuf, 768, 768);
  gemm(h, c1_b1, 0, nullptr, nullptr, 0, gbuf, NROWS, 768, 768, 1);
  smalln_k<16><<<NROWS/16, 256, 0, stream>>>(gbuf, c1_w2, c1_b2, cbuf, flag, 0);
  ctrans_k<<<512, 256, 0, stream>>>(cbuf, ctb);
  hipMemsetAsync(yacc, 0, (size_t)32*4096*4, stream);
  hipMemsetAsync(emb_pre, 0, 2*1024*4, stream);
  hipMemsetAsync(hacc, 0, (size_t)2*16384*4, stream);
  c2mlp1_k<<<dim3(32,8), 256, 0, stream>>>(ctb, c2_w1, yacc, flag);
  silu_bias_k<<<512, 256, 0, stream>>>(yacc, c2_b1, ybf, flag);
  c2mlp2_k<<<dim3(32,8), 256, 0, stream>>>(ybf, c2_w2, emb_pre, flag);
  rmsnorm_emb_k<<<2, 256, 0, stream>>>(emb_pre, c2_b2, nemb_w, embn, flag);
  head1_k<<<dim3(64,4), 256, 0, stream>>>(embn, head1_w, hacc, flag);
  head1fin_k<<<64, 256, 0, stream>>>(hacc, head1_b, d_out, flag);

  (void)in_sizes; (void)n_in; (void)out_size; (void)ws_size;
}

// Round 5
// 2801.195 us; speedup vs baseline: 2.3979x; 1.8647x over previous
//
#include <hip/hip_runtime.h>
#include <stdint.h>

typedef unsigned short u16;
typedef unsigned int u32;

#define SS 4096
#define NROWS 8192   // B*S

__device__ __forceinline__ float bf2f(u16 u){
  union { u32 u; float f; } x; x.u = ((u32)u) << 16; return x.f;
}
__device__ __forceinline__ u16 f2bf(float f){
  union { float f; u32 u; } x; x.f = f;
  u32 r = x.u + 0x7fffu + ((x.u >> 16) & 1u);
  return (u16)(r >> 16);
}
__device__ __forceinline__ float bflo(u32 u){ union { u32 u; float f; } x; x.u = u << 16; return x.f; }
__device__ __forceinline__ float bfhi(u32 u){ union { u32 u; float f; } x; x.u = u & 0xffff0000u; return x.f; }

// flag==1: external float tensors are fp32; flag==0: bf16
__device__ __forceinline__ float ldany(const void* p, size_t i, int f){
  return f ? ((const float*)p)[i] : bf2f(((const u16*)p)[i]);
}

__global__ void detect_k(const void* anw, int* flag){
  if (threadIdx.x == 0 && blockIdx.x == 0)
    flag[0] = (((const u32*)anw)[0] == 0x3F800000u) ? 1 : 0;
}

// ---------------------------------------------------------------- transpose (any-float in -> bf16 out)
__global__ void transpose_k(const void* __restrict__ in, size_t ioff,
                            u16* __restrict__ out, int R, int C, const int* fl){
  int f = *fl;
  __shared__ u16 t[32][33];
  int c0 = blockIdx.x * 32, r0 = blockIdx.y * 32;
  int tx = threadIdx.x & 31, ty = threadIdx.x >> 5; // 32x8
  #pragma unroll
  for (int i = 0; i < 32; i += 8){
    int r = r0 + ty + i, c = c0 + tx;
    t[ty + i][tx] = (r < R && c < C) ? f2bf(ldany(in, ioff + (size_t)r * C + c, f)) : (u16)0;
  }
  __syncthreads();
  #pragma unroll
  for (int i = 0; i < 32; i += 8){
    int r = c0 + ty + i, c = r0 + tx;
    if (r < C && c < R) out[(size_t)r * R + c] = t[tx][ty + i];
  }
}

// ---------------------------------------------------------------- embed + id bits
__global__ void embed_k(const int* __restrict__ x, const int* __restrict__ idv,
                        const void* __restrict__ table, u16* __restrict__ xin,
                        const int* fl){
  int f = *fl;
  int row = blockIdx.x;
  int tok = x[row], idval = idv[row];
  for (int j = threadIdx.x; j < 288; j += 256){
    u16 o;
    if (j < 256) o = f2bf(ldany(table, (size_t)tok*256 + j, f) * 16.0f);   // * sqrt(DV)
    else o = ((idval >> (31 - (j - 256))) & 1) ? (u16)0x3F80 : (u16)0;
    xin[(size_t)row * 288 + j] = o;
  }
}

// ---------------------------------------------------------------- per-row rms scale (wave per row, 4 rows/block)
__global__ __launch_bounds__(256) void rowscale_k(const u16* __restrict__ h, float* __restrict__ s){
  int wave = threadIdx.x >> 6, lane = threadIdx.x & 63;
  int row = blockIdx.x*4 + wave;
  const u16* xp = h + (size_t)row * 768;
  float ss = 0.f;
  #pragma unroll
  for (int i = 0; i < 12; ++i){ float v = bf2f(xp[i*64 + lane]); ss += v*v; }
  #pragma unroll
  for (int o = 32; o > 0; o >>= 1) ss += __shfl_down(ss, o, 64);
  if (lane == 0) s[row] = rsqrtf(ss / 768.f + 1e-6f);
}

// ---------------------------------------------------------------- rmsnorm bf16->bf16 (wave per row)
__global__ __launch_bounds__(256) void rmsnorm_k(const u16* __restrict__ in, const void* __restrict__ w,
                          u16* __restrict__ out, const int* fl){
  int f = *fl;
  int wave = threadIdx.x >> 6, lane = threadIdx.x & 63;
  int row = blockIdx.x*4 + wave;
  const u16* xp = in + (size_t)row * 768;
  float v[12]; float ss = 0.f;
  #pragma unroll
  for (int i = 0; i < 12; ++i){ v[i] = bf2f(xp[i*64 + lane]); ss += v[i]*v[i]; }
  #pragma unroll
  for (int o = 32; o > 0; o >>= 1) ss += __shfl_down(ss, o, 64);
  float tot = __shfl(ss, 0, 64);
  float sc = rsqrtf(tot / 768.f + 1e-6f);
  u16* op = out + (size_t)row * 768;
  #pragma unroll
  for (int i = 0; i < 12; ++i)
    op[i*64 + lane] = f2bf(v[i] * sc * ldany(w, i*64 + lane, f));
}

// emb rmsnorm with fused col-bias (2 rows of 1024; bias b2 indexed i>>4)
__global__ void rmsnorm_emb_k(const float* __restrict__ in, const void* __restrict__ b2,
                              const void* __restrict__ w, float* __restrict__ out, const int* fl){
  int f = *fl;
  int row = blockIdx.x;
  const float* xp = in + (size_t)row * 1024;
  float ss = 0.f;
  for (int i = threadIdx.x; i < 1024; i += 256){
    float v = xp[i] + ldany(b2, i >> 4, f); ss += v*v;
  }
  #pragma unroll
  for (int o = 32; o > 0; o >>= 1) ss += __shfl_down(ss, o, 64);
  __shared__ float red[4];
  __shared__ float scale_s;
  int lane = threadIdx.x & 63, wv = threadIdx.x >> 6;
  if (lane == 0) red[wv] = ss;
  __syncthreads();
  if (threadIdx.x == 0){
    float tot = red[0] + red[1] + red[2] + red[3];
    scale_s = rsqrtf(tot / 1024.f + 1e-6f);
  }
  __syncthreads();
  float sc = scale_s;
  for (int i = threadIdx.x; i < 1024; i += 256)
    out[(size_t)row*1024 + i] = (xp[i] + ldany(b2, i >> 4, f)) * sc * ldany(w, i, f);
}

// ---------------------------------------------------------------- MFMA GEMM: C = A(M,K) @ BT(N,K)^T
#define BM 128
#define BN 128
#define BK 32
#define BKP 40

typedef __attribute__((ext_vector_type(8))) __bf16 bf16x8;
typedef __attribute__((ext_vector_type(4))) float f32x4;

__device__ __forceinline__ uint4 normpack(uint4 a, float s, const float* w8){
  float v[8] = {bflo(a.x),bfhi(a.x),bflo(a.y),bfhi(a.y),
                bflo(a.z),bfhi(a.z),bflo(a.w),bfhi(a.w)};
  uint4 o;
  o.x = ((u32)f2bf(v[0]*s*w8[0])) | (((u32)f2bf(v[1]*s*w8[1])) << 16);
  o.y = ((u32)f2bf(v[2]*s*w8[2])) | (((u32)f2bf(v[3]*s*w8[3])) << 16);
  o.z = ((u32)f2bf(v[4]*s*w8[4])) | (((u32)f2bf(v[5]*s*w8[5])) << 16);
  o.w = ((u32)f2bf(v[6]*s*w8[6])) | (((u32)f2bf(v[7]*s*w8[7])) << 16);
  return o;
}

// epi: 0 = out=bf16(v+bias); 1 = silu; 2 = out=silu(out)*(v+bias); 3 = out += v+bias
__global__ __launch_bounds__(256) void gemm_bt_k(
    const u16* __restrict__ A, const u16* __restrict__ BT,
    const void* __restrict__ bias, const void* __restrict__ bias2,
    const void* __restrict__ bias3, int boff,
    const float* __restrict__ ascale, const void* __restrict__ anw, int aoff,
    u16* __restrict__ out, int M, int N, int K, int epi, const int* fl)
{
  __shared__ u16 As[BM*BKP];
  __shared__ u16 Bs[BN*BKP];
  const int f = *fl;
  const int tid = threadIdx.x;
  const int wave = tid >> 6, lane = tid & 63;
  const int m0 = blockIdx.y * BM, n0 = blockIdx.x * BN;
  const int wr = (wave >> 1) * 64, wc = (wave & 1) * 64;
  const int lr = lane & 15, lq = lane >> 4;

  f32x4 acc[4][4];
  #pragma unroll
  for (int i = 0; i < 4; ++i)
    #pragma unroll
    for (int j = 0; j < 4; ++j) acc[i][j] = f32x4{0.f,0.f,0.f,0.f};

  const int rA0 = tid >> 2, rA1 = rA0 + 64;
  const int cA  = (tid & 3) * 8;
  const u16* pa0 = A + (size_t)(m0 + rA0) * K + cA;
  const u16* pa1 = A + (size_t)(m0 + rA1) * K + cA;
  const u16* pb0 = BT + (size_t)(n0 + rA0) * K + cA;
  const u16* pb1 = BT + (size_t)(n0 + rA1) * K + cA;
  float s0 = 1.f, s1 = 1.f;
  if (ascale){ s0 = ascale[m0 + rA0]; s1 = ascale[m0 + rA1]; }

  for (int kt = 0; kt < K; kt += BK){
    uint4 va0 = *(const uint4*)(pa0 + kt);
    uint4 va1 = *(const uint4*)(pa1 + kt);
    uint4 vb0 = *(const uint4*)(pb0 + kt);
    uint4 vb1 = *(const uint4*)(pb1 + kt);
    if (anw){
      float w8[8];
      #pragma unroll
      for (int j = 0; j < 8; ++j) w8[j] = ldany(anw, (size_t)(aoff + cA + kt + j), f);
      va0 = normpack(va0, s0, w8);
      va1 = normpack(va1, s1, w8);
    }
    __syncthreads();
    *(uint4*)(As + rA0 * BKP + cA) = va0;
    *(uint4*)(As + rA1 * BKP + cA) = va1;
    *(uint4*)(Bs + rA0 * BKP + cA) = vb0;
    *(uint4*)(Bs + rA1 * BKP + cA) = vb1;
    __syncthreads();
    bf16x8 af[4], bfr[4];
    #pragma unroll
    for (int i = 0; i < 4; ++i)
      af[i] = *(const bf16x8*)(As + (wr + i*16 + lr) * BKP + lq*8);
    #pragma unroll
    for (int j = 0; j < 4; ++j)
      bfr[j] = *(const bf16x8*)(Bs + (wc + j*16 + lr) * BKP + lq*8);
    #pragma unroll
    for (int i = 0; i < 4; ++i)
      #pragma unroll
      for (int j = 0; j < 4; ++j)
        acc[i][j] = __builtin_amdgcn_mfma_f32_16x16x32_bf16(af[i], bfr[j], acc[i][j], 0, 0, 0);
  }

  #pragma unroll
  for (int i = 0; i < 4; ++i){
    #pragma unroll
    for (int j = 0; j < 4; ++j){
      #pragma unroll
      for (int r = 0; r < 4; ++r){
        int row = m0 + wr + i*16 + lq*4 + r;
        int col = n0 + wc + j*16 + lr;
        size_t idx = (size_t)row * N + col;
        float bb;
        if (bias3){
          if (col < 768) bb = ldany(bias, boff + col, f);
          else if (col < 1536) bb = ldany(bias2, boff + col - 768, f);
          else bb = ldany(bias3, boff + col - 1536, f);
        } else {
          bb = ldany(bias, boff + col, f);
        }
        float v = acc[i][j][r] + bb;
        if (epi == 0){
          out[idx] = f2bf(v);
        } else if (epi == 1){
          out[idx] = f2bf(v / (1.f + __expf(-v)));
        } else if (epi == 2){
          float g = bf2f(out[idx]);
          out[idx] = f2bf((g / (1.f + __expf(-g))) * v);
        } else {
          out[idx] = f2bf(bf2f(out[idx]) + v);
        }
      }
    }
  }
}

// ---------------------------------------------------------------- MFMA flash sliding attention
// block = 4 waves; one (b, head, 128-row q-chunk); wave owns 32 q rows.
// K tiles of 64 keys; Ks natural (n,d) ld=72; Vt transposed (d,n) ld=72;
// P per-wave LDS round trip (C-layout -> A-layout).
__global__ __launch_bounds__(256) void attn_mfma_k(
    const u16* __restrict__ qkv, u16* __restrict__ h)
{
  __shared__ u16 Ks[64*72];
  __shared__ u16 Vt[64*72];
  __shared__ u16 Pl[4*32*72];
  const int qc = blockIdx.x, hh = blockIdx.y, b = blockIdx.z;
  const int q0 = qc * 128;
  const int tid = threadIdx.x, wave = tid >> 6, lane = tid & 63;
  const int lr = lane & 15, lq = lane >> 4;
  u16* Pw = Pl + wave*32*72;
  const int qrow = q0 + wave*32;

  // Q A-frags in registers for the whole kernel (scale folded into scores later)
  bf16x8 qf[2][2];
  #pragma unroll
  for (int i = 0; i < 2; ++i)
    #pragma unroll
    for (int kq = 0; kq < 2; ++kq)
      qf[i][kq] = *(const bf16x8*)(qkv + (size_t)(b*SS + qrow + i*16 + lr)*2304 + hh*64 + kq*32 + lq*8);

  float m_r[2][4], l_r[2][4];
  f32x4 acc[2][4];
  #pragma unroll
  for (int i = 0; i < 2; ++i)
    #pragma unroll
    for (int r = 0; r < 4; ++r){ m_r[i][r] = -1e30f; l_r[i][r] = 0.f; }
  #pragma unroll
  for (int i = 0; i < 2; ++i)
    #pragma unroll
    for (int j = 0; j < 4; ++j) acc[i][j] = f32x4{0.f,0.f,0.f,0.f};

  for (int jt = 0; jt < 10; ++jt){
    int t0 = q0 - 256 + jt*64;
    if (t0 + 64 <= 0 || t0 >= SS) continue;   // uniform per block

    // stage K natural: thread -> row n=tid>>2, d-part (tid&3)*16
    {
      int n = tid >> 2, dp = (tid & 3) * 16;
      int kg = t0 + n;
      uint4 a = {0,0,0,0}, c = {0,0,0,0};
      if (kg >= 0 && kg < SS){
        const u16* kp = qkv + (size_t)(b*SS+kg)*2304 + 768 + hh*64 + dp;
        a = *(const uint4*)kp; c = *(const uint4*)(kp + 8);
      }
      *(uint4*)(Ks + n*72 + dp)     = a;
      *(uint4*)(Ks + n*72 + dp + 8) = c;
    }
    // stage V transposed: wave owns d-slab [wave*16, +16), lane owns row n=lane
    {
      int n = lane, dp = wave*16;
      int kg = t0 + n;
      uint4 a = {0,0,0,0}, c = {0,0,0,0};
      if (kg >= 0 && kg < SS){
        const u16* vp = qkv + (size_t)(b*SS+kg)*2304 + 1536 + hh*64 + dp;
        a = *(const uint4*)vp; c = *(const uint4*)(vp + 8);
      }
      u32 w[8] = {a.x,a.y,a.z,a.w,c.x,c.y,c.z,c.w};
      #pragma unroll
      for (int e = 0; e < 8; ++e){
        Vt[(dp + e*2    )*72 + n] = (u16)(w[e] & 0xffffu);
        Vt[(dp + e*2 + 1)*72 + n] = (u16)(w[e] >> 16);
      }
    }
    __syncthreads();

    // QK^T -> scores (C-layout)
    f32x4 sc[2][4];
    #pragma unroll
    for (int i = 0; i < 2; ++i)
      #pragma unroll
      for (int j = 0; j < 4; ++j) sc[i][j] = f32x4{0.f,0.f,0.f,0.f};
    #pragma unroll
    for (int j = 0; j < 4; ++j){
      bf16x8 kfa = *(const bf16x8*)(Ks + (j*16 + lr)*72 + lq*8);
      bf16x8 kfb = *(const bf16x8*)(Ks + (j*16 + lr)*72 + 32 + lq*8);
      #pragma unroll
      for (int i = 0; i < 2; ++i){
        sc[i][j] = __builtin_amdgcn_mfma_f32_16x16x32_bf16(qf[i][0], kfa, sc[i][j], 0, 0, 0);
        sc[i][j] = __builtin_amdgcn_mfma_f32_16x16x32_bf16(qf[i][1], kfb, sc[i][j], 0, 0, 0);
      }
    }

    // scale + band/bounds mask
    #pragma unroll
    for (int i = 0; i < 2; ++i){
      #pragma unroll
      for (int r = 0; r < 4; ++r){
        int qg = qrow + i*16 + lq*4 + r;
        #pragma unroll
        for (int j = 0; j < 4; ++j){
          int kg = t0 + j*16 + lr;
          float s = sc[i][j][r] * 0.125f;
          bool ok = (kg >= 0) && (kg < SS) && (kg >= qg - 256) && (kg <= qg + 256);
          sc[i][j][r] = ok ? s : -1e38f;
        }
      }
    }

    // online softmax (row state replicated across the 16 lanes of each quad)
    #pragma unroll
    for (int i = 0; i < 2; ++i){
      #pragma unroll
      for (int r = 0; r < 4; ++r){
        float mx = fmaxf(fmaxf(sc[i][0][r], sc[i][1][r]), fmaxf(sc[i][2][r], sc[i][3][r]));
        #pragma unroll
        for (int o = 1; o < 16; o <<= 1) mx = fmaxf(mx, __shfl_xor(mx, o, 64));
        float mn = fmaxf(m_r[i][r], mx);   // clamped >= -1e30 -> no NaN
        float al = __expf(m_r[i][r] - mn);
        float ps = 0.f;
        #pragma unroll
        for (int j = 0; j < 4; ++j){
          float p = __expf(sc[i][j][r] - mn);
          sc[i][j][r] = p; ps += p;
        }
        #pragma unroll
        for (int o = 1; o < 16; o <<= 1) ps += __shfl_xor(ps, o, 64);
        l_r[i][r] = l_r[i][r] * al + ps;
        m_r[i][r] = mn;
        #pragma unroll
        for (int j = 0; j < 4; ++j) acc[i][j][r] *= al;
      }
    }

    // P: C-layout -> LDS (m,n) bf16
    #pragma unroll
    for (int i = 0; i < 2; ++i)
      #pragma unroll
      for (int j = 0; j < 4; ++j)
        #pragma unroll
        for (int r = 0; r < 4; ++r)
          Pw[(i*16 + lq*4 + r)*72 + j*16 + lr] = f2bf(sc[i][j][r]);

    // PV: A-frags from Pw, B-frags from Vt
    #pragma unroll
    for (int kq = 0; kq < 2; ++kq){
      bf16x8 pf0 = *(const bf16x8*)(Pw + lr*72        + kq*32 + lq*8);
      bf16x8 pf1 = *(const bf16x8*)(Pw + (16 + lr)*72 + kq*32 + lq*8);
      #pragma unroll
      for (int j = 0; j < 4; ++j){
        bf16x8 vfj = *(const bf16x8*)(Vt + (j*16 + lr)*72 + kq*32 + lq*8);
        acc[0][j] = __builtin_amdgcn_mfma_f32_16x16x32_bf16(pf0, vfj, acc[0][j], 0, 0, 0);
        acc[1][j] = __builtin_amdgcn_mfma_f32_16x16x32_bf16(pf1, vfj, acc[1][j], 0, 0, 0);
      }
    }
    __syncthreads();
  }

  // epilogue: h += O / l
  #pragma unroll
  for (int i = 0; i < 2; ++i){
    #pragma unroll
    for (int r = 0; r < 4; ++r){
      float inv = 1.f / l_r[i][r];
      int qg = qrow + i*16 + lq*4 + r;
      u16* hp = h + (size_t)(b*SS + qg)*768 + hh*64;
      #pragma unroll
      for (int j = 0; j < 4; ++j){
        int d = j*16 + lr;
        hp[d] = f2bf(bf2f(hp[d]) + acc[i][j][r] * inv);
      }
    }
  }
}

// ---------------------------------------------------------------- small-N projection (wave/row, LDS W)
template<int NN>
__global__ __launch_bounds__(256) void smalln_k(const u16* __restrict__ A, const void* __restrict__ W,
                         const void* __restrict__ bias, void* __restrict__ out,
                         const int* fl, int outmode){
  int f = *fl;
  __shared__ float Wl[NN*768];
  for (int i = threadIdx.x; i < NN*768; i += 256){
    int n = i / 768, k = i - n*768;
    Wl[i] = ldany(W, (size_t)k*NN + n, f);
  }
  __syncthreads();
  int wave = threadIdx.x >> 6, lane = threadIdx.x & 63;
  int rowbase = blockIdx.x*16 + wave*4;
  for (int r = 0; r < 4; ++r){
    int row = rowbase + r;
    const u16* ap = A + (size_t)row * 768;
    float a[12];
    #pragma unroll
    for (int i = 0; i < 12; ++i) a[i] = bf2f(ap[i*64 + lane]);
    float acc[NN];
    #pragma unroll
    for (int n = 0; n < NN; ++n) acc[n] = 0.f;
    #pragma unroll
    for (int i = 0; i < 12; ++i){
      int k = i*64 + lane;
      #pragma unroll
      for (int n = 0; n < NN; ++n) acc[n] += a[i] * Wl[n*768 + k];
    }
    float red[NN];
    #pragma unroll
    for (int n = 0; n < NN; ++n){
      float v = acc[n];
      #pragma unroll
      for (int o = 32; o > 0; o >>= 1) v += __shfl_down(v, o, 64);
      red[n] = v;
    }
    if (lane == 0){
      #pragma unroll
      for (int n = 0; n < NN; ++n){
        float v = red[n] + ldany(bias, n, f);
        size_t oi = (size_t)row*NN + n;
        if (outmode && f) ((float*)out)[oi] = v;
        else ((u16*)out)[oi] = f2bf(v);
      }
    }
  }
}

// ---------------------------------------------------------------- c path
__global__ void ctrans_k(const u16* __restrict__ in, u16* __restrict__ out){
  int idx = blockIdx.x * 256 + threadIdx.x;   // 2*16*4096
  int b = idx >> 16;
  int r = idx & 65535;
  int d = r >> 12, s = r & 4095;
  out[idx] = in[(size_t)(b*4096 + s)*16 + d];
}

// ct (32,4096) @ w (4096,4096 external), K-split atomics into yacc (32,4096) f32
__global__ __launch_bounds__(256) void c2mlp1_k(const u16* __restrict__ ct,
    const void* __restrict__ w, float* __restrict__ yacc, const int* fl){
  int f = *fl;
  __shared__ float Awt[64][36];
  __shared__ u16 Ws[64*128];
  int n0 = blockIdx.x * 128;
  int k0 = blockIdx.y * 512;
  int tid = threadIdx.x;
  int c4 = (tid & 31) * 4;
  int r0 = (tid >> 5) * 4;
  float acc[4][4] = {};
  for (int ks = 0; ks < 512; ks += 64){
    __syncthreads();
    {
      int mm = tid >> 3, kk8 = (tid & 7) * 8;
      uint4 av = *(const uint4*)(ct + (size_t)mm*4096 + k0 + ks + kk8);
      float fv[8] = {bflo(av.x),bfhi(av.x),bflo(av.y),bfhi(av.y),
                     bflo(av.z),bfhi(av.z),bflo(av.w),bfhi(av.w)};
      #pragma unroll
      for (int i = 0; i < 8; ++i) Awt[kk8+i][mm] = fv[i];
    }
    {
      int kk = tid >> 2, cc = (tid & 3) * 32;
      #pragma unroll
      for (int j = 0; j < 32; ++j)
        Ws[kk*128 + cc + j] = f2bf(ldany(w, (size_t)(k0+ks+kk)*4096 + n0 + cc + j, f));
    }
    __syncthreads();
    for (int kk = 0; kk < 64; ++kk){
      float4 a4 = *(const float4*)&Awt[kk][r0];
      uint2 wv = *(const uint2*)(Ws + kk*128 + c4);
      float w0 = bflo(wv.x), w1v = bfhi(wv.x), w2v = bflo(wv.y), w3v = bfhi(wv.y);
      float ar[4] = {a4.x, a4.y, a4.z, a4.w};
      #pragma unroll
      for (int r = 0; r < 4; ++r){
        acc[r][0] += ar[r]*w0;  acc[r][1] += ar[r]*w1v;
        acc[r][2] += ar[r]*w2v; acc[r][3] += ar[r]*w3v;
      }
    }
  }
  #pragma unroll
  for (int r = 0; r < 4; ++r)
    #pragma unroll
    for (int cc = 0; cc < 4; ++cc)
      atomicAdd(&yacc[(size_t)(r0+r)*4096 + n0 + c4 + cc], acc[r][cc]);
}

__global__ void silu_bias_k(const float* __restrict__ yacc, const void* __restrict__ bias,
                            u16* __restrict__ out, const int* fl){
  int f = *fl;
  int idx = blockIdx.x*256 + threadIdx.x;    // 32*4096
  int n = idx & 4095;
  float v = yacc[idx] + ldany(bias, n, f);
  out[idx] = f2bf(v / (1.f + __expf(-v)));
}

// y (32,4096) @ w2 (4096,64), K-split atomics into emb_pre (bias added in rmsnorm_emb)
__global__ void c2mlp2_k(const u16* __restrict__ y, const void* __restrict__ w2,
                         float* __restrict__ emb_pre, const int* fl){
  int f = *fl;
  int m = blockIdx.x, kseg = blockIdx.y;
  int col = threadIdx.x & 63, sl = threadIdx.x >> 6;
  float acc = 0.f;
  int kb = kseg*512 + sl*128;
  for (int k = kb; k < kb+128; ++k)
    acc += bf2f(y[(size_t)m*4096 + k]) * ldany(w2, (size_t)k*64 + col, f);
  __shared__ float red[256];
  red[threadIdx.x] = acc;
  __syncthreads();
  if (sl == 0){
    float t = red[col] + red[col+64] + red[col+128] + red[col+192];
    int b = m >> 4, d = m & 15;
    atomicAdd(&emb_pre[b*1024 + col*16 + d], t);
  }
}

// head1: K-split atomics into hacc, then finish with bias
__global__ void head1_k(const float* __restrict__ emb, const void* __restrict__ w,
                        float* __restrict__ hacc, const int* fl){
  int f = *fl;
  int n = blockIdx.x*256 + threadIdx.x;    // 16384
  int k0 = blockIdx.y*256;
  float a0 = 0.f, a1 = 0.f;
  for (int k = k0; k < k0+256; ++k){
    float wv = ldany(w, (size_t)k*16384 + n, f);
    a0 += emb[k] * wv;
    a1 += emb[1024 + k] * wv;
  }
  atomicAdd(&hacc[n], a0);
  atomicAdd(&hacc[16384 + n], a1);
}

__global__ void head1fin_k(const float* __restrict__ hacc, const void* __restrict__ bias,
                           void* __restrict__ out, const int* fl){
  int f = *fl;
  int n = blockIdx.x*256 + threadIdx.x;
  float b = ldany(bias, n, f);
  float a0 = hacc[n] + b, a1 = hacc[16384 + n] + b;
  if (f){ ((float*)out)[32768 + n] = a0; ((float*)out)[49152 + n] = a1; }
  else  { ((u16*)out)[32768 + n] = f2bf(a0); ((u16*)out)[49152 + n] = f2bf(a1); }
}

// ================================================================ host
extern "C" void kernel_launch(void* const* d_in, const int* in_sizes, int n_in,
                              void* d_out, int out_size, void* d_ws, size_t ws_size,
                              hipStream_t stream)
{
  const int* x   = (const int*)d_in[0];
  const int* idv = (const int*)d_in[1];
  const void* embt = d_in[2];
  const void* cd_w = d_in[3];
  const void* cd_b = d_in[4];
  const void* wq = d_in[5];
  const void* bq = d_in[6];
  const void* wk = d_in[7];
  const void* bk = d_in[8];
  const void* wv = d_in[9];
  const void* bv = d_in[10];
  const void* attn_nw = d_in[11];
  const void* ffn_nw  = d_in[12];
  const void* w1 = d_in[13];
  const void* b1 = d_in[14];
  const void* w2 = d_in[15];
  const void* b2 = d_in[16];
  const void* w3 = d_in[17];
  const void* b3 = d_in[18];
  const void* h0_w1 = d_in[19];
  const void* h0_b1 = d_in[20];
  const void* h0_w2 = d_in[21];
  const void* h0_b2 = d_in[22];
  const void* nh0_w = d_in[23];
  const void* head0_w = d_in[24];
  const void* head0_b = d_in[25];
  const void* c1_w1 = d_in[26];
  const void* c1_b1 = d_in[27];
  const void* c1_w2 = d_in[28];
  const void* c1_b2 = d_in[29];
  const void* c2_w1 = d_in[30];
  const void* c2_b1 = d_in[31];
  const void* c2_w2 = d_in[32];
  const void* c2_b2 = d_in[33];
  const void* nemb_w = d_in[34];
  const void* head1_w = d_in[35];
  const void* head1_b = d_in[36];

  char* ws = (char*)d_ws;
  size_t off = 0;
  auto alloc = [&](size_t bytes)->char*{
    char* p = ws + off; off = (off + bytes + 255) & ~(size_t)255; return p;
  };

  int*  flag  = (int*)alloc(256);
  u16*  wtbuf = (u16*)alloc((size_t)2304*768*2);        // rotating transposed-weight buffer (bf16)
  u16*  h     = (u16*)alloc((size_t)NROWS*768*2);       // residual stream bf16
  float* rs   = (float*)alloc((size_t)NROWS*4);         // per-row rms scales
  char* R3    = alloc((size_t)NROWS*768*2*3);           // 37.75MB union scratch

  u16* xin  = (u16*)R3;                                  // (8192,288)
  u16* qkvb = (u16*)R3;                                  // (8192,2304) fused QKV
  u16* g1   = (u16*)R3;                                  // (8192,2048)
  u16* tbuf = (u16*)R3;                                  // (8192,768)
  u16* gbuf = (u16*)(R3 + (size_t)NROWS*768*2);          // (8192,768)
  char* tail = R3 + (size_t)NROWS*768*2*2;
  u16* cbuf = (u16*)tail;                                // (8192,16)
  u16* ctb  = (u16*)(tail + 262144);                     // (32,4096)
  float* yacc = (float*)(tail + 262144*2);               // (32,4096) f32
  u16* ybf  = (u16*)(tail + 262144*2 + 524288);          // (32,4096)
  float* emb_pre = (float*)(tail + 262144*3 + 524288);   // (2,1024) f32
  float* embn    = (float*)(tail + 262144*3 + 524288 + 8192);
  float* hacc    = (float*)(tail + 262144*3 + 524288 + 16384); // (2,16384) f32

  detect_k<<<1, 64, 0, stream>>>(attn_nw, flag);

  auto tr = [&](const void* src, size_t ioff, u16* dst, int R, int C){
    dim3 g((C+31)/32, (R+31)/32);
    transpose_k<<<g, 256, 0, stream>>>(src, ioff, dst, R, C, flag);
  };
  auto gemm = [&](const u16* A, const void* bias, int boff,
                  const float* ascale, const void* anw, int aoff,
                  u16* out_, int M, int N, int K, int epi){
    dim3 g(N/128, M/128);
    gemm_bt_k<<<g, 256, 0, stream>>>(A, wtbuf, bias, nullptr, nullptr, boff,
                                     ascale, anw, aoff, out_, M, N, K, epi, flag);
  };

  // embed + concat-id -> xin;  h = xin @ cd_w + cd_b
  embed_k<<<NROWS, 256, 0, stream>>>(x, idv, embt, xin, flag);
  tr(cd_w, 0, wtbuf, 288, 768);
  gemm(xin, cd_b, 0, nullptr, nullptr, 0, h, NROWS, 768, 288, 0);

  for (int l = 0; l < 4; ++l){
    size_t wo = (size_t)l*768*768, fo = (size_t)l*768*2048;
    rowscale_k<<<NROWS/4, 256, 0, stream>>>(h, rs);
    // fused QKV: wtbuf rows [0,768)=wq^T, [768,1536)=wk^T, [1536,2304)=wv^T
    tr(wq, wo, wtbuf,              768, 768);
    tr(wk, wo, wtbuf + 768*768,    768, 768);
    tr(wv, wo, wtbuf + 2*768*768,  768, 768);
    {
      dim3 g(2304/128, NROWS/128);
      gemm_bt_k<<<g, 256, 0, stream>>>(h, wtbuf, bq, bk, bv, l*768,
                                       rs, attn_nw, l*768, qkvb, NROWS, 2304, 768, 0, flag);
    }
    attn_mfma_k<<<dim3(32,12,2), 256, 0, stream>>>(qkvb, h);

    rowscale_k<<<NROWS/4, 256, 0, stream>>>(h, rs);
    tr(w1, fo, wtbuf, 768, 2048);
    gemm(h, b1, l*2048, rs, ffn_nw, l*768, g1, NROWS, 2048, 768, 0);
    tr(w3, fo, wtbuf, 768, 2048);
    gemm(h, b3, l*2048, rs, ffn_nw, l*768, g1, NROWS, 2048, 768, 2);  // in-place gate
    tr(w2, fo, wtbuf, 2048, 768);
    gemm(g1, b2, l*768, nullptr, nullptr, 0, h, NROWS, 768, 2048, 3); // residual
  }

  // head0 path
  tr(h0_w1, 0, wtbuf, 768, 768);
  gemm(h, h0_b1, 0, nullptr, nullptr, 0, gbuf, NROWS, 768, 768, 1);
  tr(h0_w2, 0, wtbuf, 768, 768);
  gemm(gbuf, h0_b2, 0, nullptr, nullptr, 0, tbuf, NROWS, 768, 768, 0);
  rmsnorm_k<<<NROWS/4, 256, 0, stream>>>(tbuf, nh0_w, gbuf, flag);
  smalln_k<4><<<NROWS/16, 256, 0, stream>>>(gbuf, head0_w, head0_b, d_out, flag, 1);

  // c path
  tr(c1_w1, 0, wtbuf, 768, 768);
  gemm(h, c1_b1, 0, nullptr, nullptr, 0, gbuf, NROWS, 768, 768, 1);
  smalln_k<16><<<NROWS/16, 256, 0, stream>>>(gbuf, c1_w2, c1_b2, cbuf, flag, 0);
  ctrans_k<<<512, 256, 0, stream>>>(cbuf, ctb);
  hipMemsetAsync(yacc, 0, (size_t)32*4096*4, stream);
  hipMemsetAsync(emb_pre, 0, 2*1024*4, stream);
  hipMemsetAsync(hacc, 0, (size_t)2*16384*4, stream);
  c2mlp1_k<<<dim3(32,8), 256, 0, stream>>>(ctb, c2_w1, yacc, flag);
  silu_bias_k<<<512, 256, 0, stream>>>(yacc, c2_b1, ybf, flag);
  c2mlp2_k<<<dim3(32,8), 256, 0, stream>>>(ybf, c2_w2, emb_pre, flag);
  rmsnorm_emb_k<<<2, 256, 0, stream>>>(emb_pre, c2_b2, nemb_w, embn, flag);
  head1_k<<<dim3(64,4), 256, 0, stream>>>(embn, head1_w, hacc, flag);
  head1fin_k<<<64, 256, 0, stream>>>(hacc, head1_b, d_out, flag);

  (void)in_sizes; (void)n_in; (void)out_size; (void)ws_size;
}

// Round 6
// 2501.149 us; speedup vs baseline: 2.6856x; 1.1200x over previous
//
#include <hip/hip_runtime.h>
#include <stdint.h>

typedef unsigned short u16;
typedef unsigned int u32;

#define SS 4096
#define NROWS 8192   // B*S

__device__ __forceinline__ float bf2f(u16 u){
  union { u32 u; float f; } x; x.u = ((u32)u) << 16; return x.f;
}
__device__ __forceinline__ u16 f2bf(float f){
  union { float f; u32 u; } x; x.f = f;
  u32 r = x.u + 0x7fffu + ((x.u >> 16) & 1u);
  return (u16)(r >> 16);
}
__device__ __forceinline__ float bflo(u32 u){ union { u32 u; float f; } x; x.u = u << 16; return x.f; }
__device__ __forceinline__ float bfhi(u32 u){ union { u32 u; float f; } x; x.u = u & 0xffff0000u; return x.f; }

// flag==1: external float tensors are fp32; flag==0: bf16
__device__ __forceinline__ float ldany(const void* p, size_t i, int f){
  return f ? ((const float*)p)[i] : bf2f(((const u16*)p)[i]);
}

__global__ void detect_k(const void* anw, int* flag){
  if (threadIdx.x == 0 && blockIdx.x == 0)
    flag[0] = (((const u32*)anw)[0] == 0x3F800000u) ? 1 : 0;
}

// async global->LDS, 16B per lane; lds dest = wave-uniform base + lane*16
__device__ __forceinline__ void gload16(const u16* g, u16* l){
  __builtin_amdgcn_global_load_lds((const __attribute__((address_space(1))) void*)g,
                                   (__attribute__((address_space(3))) void*)l, 16, 0, 0);
}

// ---------------------------------------------------------------- transpose (any-float in -> bf16 out)
__global__ void transpose_k(const void* __restrict__ in, size_t ioff,
                            u16* __restrict__ out, int R, int C, const int* fl){
  int f = *fl;
  __shared__ u16 t[32][33];
  int c0 = blockIdx.x * 32, r0 = blockIdx.y * 32;
  int tx = threadIdx.x & 31, ty = threadIdx.x >> 5; // 32x8
  #pragma unroll
  for (int i = 0; i < 32; i += 8){
    int r = r0 + ty + i, c = c0 + tx;
    t[ty + i][tx] = (r < R && c < C) ? f2bf(ldany(in, ioff + (size_t)r * C + c, f)) : (u16)0;
  }
  __syncthreads();
  #pragma unroll
  for (int i = 0; i < 32; i += 8){
    int r = c0 + ty + i, c = r0 + tx;
    if (r < C && c < R) out[(size_t)r * R + c] = t[tx][ty + i];
  }
}

// merged QKV transpose: z selects among 3 sources (each (768,768) at offset wo)
__global__ void transpose_qkv_k(const void* __restrict__ wqp, const void* __restrict__ wkp,
                                const void* __restrict__ wvp, size_t wo,
                                u16* __restrict__ out, const int* fl){
  int f = *fl;
  const void* in = (blockIdx.z == 0) ? wqp : (blockIdx.z == 1) ? wkp : wvp;
  u16* dst = out + (size_t)blockIdx.z * 768 * 768;
  __shared__ u16 t[32][33];
  int c0 = blockIdx.x * 32, r0 = blockIdx.y * 32;
  int tx = threadIdx.x & 31, ty = threadIdx.x >> 5;
  #pragma unroll
  for (int i = 0; i < 32; i += 8){
    int r = r0 + ty + i, c = c0 + tx;
    t[ty + i][tx] = f2bf(ldany(in, wo + (size_t)r * 768 + c, f));
  }
  __syncthreads();
  #pragma unroll
  for (int i = 0; i < 32; i += 8){
    int r = c0 + ty + i, c = r0 + tx;
    dst[(size_t)r * 768 + c] = t[tx][ty + i];
  }
}

// ---------------------------------------------------------------- embed + id bits
__global__ void embed_k(const int* __restrict__ x, const int* __restrict__ idv,
                        const void* __restrict__ table, u16* __restrict__ xin,
                        const int* fl){
  int f = *fl;
  int row = blockIdx.x;
  int tok = x[row], idval = idv[row];
  for (int j = threadIdx.x; j < 288; j += 256){
    u16 o;
    if (j < 256) o = f2bf(ldany(table, (size_t)tok*256 + j, f) * 16.0f);   // * sqrt(DV)
    else o = ((idval >> (31 - (j - 256))) & 1) ? (u16)0x3F80 : (u16)0;
    xin[(size_t)row * 288 + j] = o;
  }
}

// ---------------------------------------------------------------- rmsnorm with weight offset (wave per row)
__global__ __launch_bounds__(256) void rmsnormw_k(const u16* __restrict__ in,
                          const void* __restrict__ w, int woff,
                          u16* __restrict__ out, const int* fl){
  int f = *fl;
  int wave = threadIdx.x >> 6, lane = threadIdx.x & 63;
  int row = blockIdx.x*4 + wave;
  const u16* xp = in + (size_t)row * 768;
  float v[12]; float ss = 0.f;
  #pragma unroll
  for (int i = 0; i < 12; ++i){ v[i] = bf2f(xp[i*64 + lane]); ss += v[i]*v[i]; }
  #pragma unroll
  for (int o = 32; o > 0; o >>= 1) ss += __shfl_down(ss, o, 64);
  float tot = __shfl(ss, 0, 64);
  float sc = rsqrtf(tot / 768.f + 1e-6f);
  u16* op = out + (size_t)row * 768;
  #pragma unroll
  for (int i = 0; i < 12; ++i)
    op[i*64 + lane] = f2bf(v[i] * sc * ldany(w, woff + i*64 + lane, f));
}

// emb rmsnorm with fused col-bias (2 rows of 1024; bias b2 indexed i>>4)
__global__ void rmsnorm_emb_k(const float* __restrict__ in, const void* __restrict__ b2,
                              const void* __restrict__ w, float* __restrict__ out, const int* fl){
  int f = *fl;
  int row = blockIdx.x;
  const float* xp = in + (size_t)row * 1024;
  float ss = 0.f;
  for (int i = threadIdx.x; i < 1024; i += 256){
    float v = xp[i] + ldany(b2, i >> 4, f); ss += v*v;
  }
  #pragma unroll
  for (int o = 32; o > 0; o >>= 1) ss += __shfl_down(ss, o, 64);
  __shared__ float red[4];
  __shared__ float scale_s;
  int lane = threadIdx.x & 63, wv = threadIdx.x >> 6;
  if (lane == 0) red[wv] = ss;
  __syncthreads();
  if (threadIdx.x == 0){
    float tot = red[0] + red[1] + red[2] + red[3];
    scale_s = rsqrtf(tot / 1024.f + 1e-6f);
  }
  __syncthreads();
  float sc = scale_s;
  for (int i = threadIdx.x; i < 1024; i += 256)
    out[(size_t)row*1024 + i] = (xp[i] + ldany(b2, i >> 4, f)) * sc * ldany(w, i, f);
}

// ---------------------------------------------------------------- MFMA GEMM (m97 structure): C = A(M,K) @ BT(N,K)^T
#define BM 128
#define BN 128
#define BK 32

typedef __attribute__((ext_vector_type(8))) __bf16 bf16x8;
typedef __attribute__((ext_vector_type(4))) float f32x4;

// epi: 0 = out=bf16(v+bias); 1 = silu; 2 = out=silu(out)*(v+bias); 3 = out += v+bias
__global__ __launch_bounds__(256) void gemm_bt_k(
    const u16* __restrict__ A, const u16* __restrict__ BT,
    const void* __restrict__ bias, const void* __restrict__ bias2,
    const void* __restrict__ bias3, int boff,
    u16* __restrict__ out, int M, int N, int K, int epi, const int* fl)
{
  __shared__ u16 As[BM*BK];
  __shared__ u16 Bs[BN*BK];
  const int f = *fl;
  const int tid = threadIdx.x;
  const int wave = tid >> 6, lane = tid & 63;
  const int m0 = blockIdx.y * BM, n0 = blockIdx.x * BN;
  const int wr = (wave >> 1) * 64, wc = (wave & 1) * 64;
  const int lr = lane & 15, lq = lane >> 4;

  f32x4 acc[4][4];
  #pragma unroll
  for (int i = 0; i < 4; ++i)
    #pragma unroll
    for (int j = 0; j < 4; ++j) acc[i][j] = f32x4{0.f,0.f,0.f,0.f};

  // staging: wave w stages rows [w*32, w*32+32) of A-tile and B-tile.
  // per issue: 64 lanes x 16B = 16 rows x 32 bf16 (lane -> row lane>>2, col (lane&3)*8)
  const int r_in = lane >> 2;
  const int c_in = (lane & 3) * 8;
  const u16* gA = A  + (size_t)(m0 + wave*32 + r_in) * K + c_in;
  const u16* gB = BT + (size_t)(n0 + wave*32 + r_in) * K + c_in;
  u16* lA = As + wave*32*BK;
  u16* lB = Bs + wave*32*BK;

  for (int kt = 0; kt < K; kt += BK){
    __syncthreads();                        // prev compute done (LDS safe to overwrite)
    gload16(gA + kt,        lA);
    gload16(gA + kt + 16*K, lA + 16*BK);
    gload16(gB + kt,        lB);
    gload16(gB + kt + 16*K, lB + 16*BK);
    __syncthreads();                        // vmcnt(0) drain at barrier -> data visible
    bf16x8 af[4], bfr[4];
    #pragma unroll
    for (int i = 0; i < 4; ++i)
      af[i] = *(const bf16x8*)(As + (wr + i*16 + lr) * BK + lq*8);
    #pragma unroll
    for (int j = 0; j < 4; ++j)
      bfr[j] = *(const bf16x8*)(Bs + (wc + j*16 + lr) * BK + lq*8);
    #pragma unroll
    for (int i = 0; i < 4; ++i)
      #pragma unroll
      for (int j = 0; j < 4; ++j)
        acc[i][j] = __builtin_amdgcn_mfma_f32_16x16x32_bf16(af[i], bfr[j], acc[i][j], 0, 0, 0);
  }

  #pragma unroll
  for (int i = 0; i < 4; ++i){
    #pragma unroll
    for (int j = 0; j < 4; ++j){
      #pragma unroll
      for (int r = 0; r < 4; ++r){
        int row = m0 + wr + i*16 + lq*4 + r;
        int col = n0 + wc + j*16 + lr;
        size_t idx = (size_t)row * N + col;
        float bb;
        if (bias3){
          if (col < 768) bb = ldany(bias, boff + col, f);
          else if (col < 1536) bb = ldany(bias2, boff + col - 768, f);
          else bb = ldany(bias3, boff + col - 1536, f);
        } else {
          bb = ldany(bias, boff + col, f);
        }
        float v = acc[i][j][r] + bb;
        if (epi == 0){
          out[idx] = f2bf(v);
        } else if (epi == 1){
          out[idx] = f2bf(v / (1.f + __expf(-v)));
        } else if (epi == 2){
          float g = bf2f(out[idx]);
          out[idx] = f2bf((g / (1.f + __expf(-g))) * v);
        } else {
          out[idx] = f2bf(bf2f(out[idx]) + v);
        }
      }
    }
  }
}

// ---------------------------------------------------------------- MFMA flash sliding attention
__global__ __launch_bounds__(256) void attn_mfma_k(
    const u16* __restrict__ qkv, u16* __restrict__ h)
{
  __shared__ u16 Ks[64*72];
  __shared__ u16 Vt[64*72];
  __shared__ u16 Pl[4*32*72];
  const int qc = blockIdx.x, hh = blockIdx.y, b = blockIdx.z;
  const int q0 = qc * 128;
  const int tid = threadIdx.x, wave = tid >> 6, lane = tid & 63;
  const int lr = lane & 15, lq = lane >> 4;
  u16* Pw = Pl + wave*32*72;
  const int qrow = q0 + wave*32;

  bf16x8 qf[2][2];
  #pragma unroll
  for (int i = 0; i < 2; ++i)
    #pragma unroll
    for (int kq = 0; kq < 2; ++kq)
      qf[i][kq] = *(const bf16x8*)(qkv + (size_t)(b*SS + qrow + i*16 + lr)*2304 + hh*64 + kq*32 + lq*8);

  float m_r[2][4], l_r[2][4];
  f32x4 acc[2][4];
  #pragma unroll
  for (int i = 0; i < 2; ++i)
    #pragma unroll
    for (int r = 0; r < 4; ++r){ m_r[i][r] = -1e30f; l_r[i][r] = 0.f; }
  #pragma unroll
  for (int i = 0; i < 2; ++i)
    #pragma unroll
    for (int j = 0; j < 4; ++j) acc[i][j] = f32x4{0.f,0.f,0.f,0.f};

  for (int jt = 0; jt < 10; ++jt){
    int t0 = q0 - 256 + jt*64;
    if (t0 + 64 <= 0 || t0 >= SS) continue;   // uniform per block

    {
      int n = tid >> 2, dp = (tid & 3) * 16;
      int kg = t0 + n;
      uint4 a = {0,0,0,0}, c = {0,0,0,0};
      if (kg >= 0 && kg < SS){
        const u16* kp = qkv + (size_t)(b*SS+kg)*2304 + 768 + hh*64 + dp;
        a = *(const uint4*)kp; c = *(const uint4*)(kp + 8);
      }
      *(uint4*)(Ks + n*72 + dp)     = a;
      *(uint4*)(Ks + n*72 + dp + 8) = c;
    }
    {
      int n = lane, dp = wave*16;
      int kg = t0 + n;
      uint4 a = {0,0,0,0}, c = {0,0,0,0};
      if (kg >= 0 && kg < SS){
        const u16* vp = qkv + (size_t)(b*SS+kg)*2304 + 1536 + hh*64 + dp;
        a = *(const uint4*)vp; c = *(const uint4*)(vp + 8);
      }
      u32 w[8] = {a.x,a.y,a.z,a.w,c.x,c.y,c.z,c.w};
      #pragma unroll
      for (int e = 0; e < 8; ++e){
        Vt[(dp + e*2    )*72 + n] = (u16)(w[e] & 0xffffu);
        Vt[(dp + e*2 + 1)*72 + n] = (u16)(w[e] >> 16);
      }
    }
    __syncthreads();

    f32x4 sc[2][4];
    #pragma unroll
    for (int i = 0; i < 2; ++i)
      #pragma unroll
      for (int j = 0; j < 4; ++j) sc[i][j] = f32x4{0.f,0.f,0.f,0.f};
    #pragma unroll
    for (int j = 0; j < 4; ++j){
      bf16x8 kfa = *(const bf16x8*)(Ks + (j*16 + lr)*72 + lq*8);
      bf16x8 kfb = *(const bf16x8*)(Ks + (j*16 + lr)*72 + 32 + lq*8);
      #pragma unroll
      for (int i = 0; i < 2; ++i){
        sc[i][j] = __builtin_amdgcn_mfma_f32_16x16x32_bf16(qf[i][0], kfa, sc[i][j], 0, 0, 0);
        sc[i][j] = __builtin_amdgcn_mfma_f32_16x16x32_bf16(qf[i][1], kfb, sc[i][j], 0, 0, 0);
      }
    }

    #pragma unroll
    for (int i = 0; i < 2; ++i){
      #pragma unroll
      for (int r = 0; r < 4; ++r){
        int qg = qrow + i*16 + lq*4 + r;
        #pragma unroll
        for (int j = 0; j < 4; ++j){
          int kg = t0 + j*16 + lr;
          float s = sc[i][j][r] * 0.125f;
          bool ok = (kg >= 0) && (kg < SS) && (kg >= qg - 256) && (kg <= qg + 256);
          sc[i][j][r] = ok ? s : -1e38f;
        }
      }
    }

    #pragma unroll
    for (int i = 0; i < 2; ++i){
      #pragma unroll
      for (int r = 0; r < 4; ++r){
        float mx = fmaxf(fmaxf(sc[i][0][r], sc[i][1][r]), fmaxf(sc[i][2][r], sc[i][3][r]));
        #pragma unroll
        for (int o = 1; o < 16; o <<= 1) mx = fmaxf(mx, __shfl_xor(mx, o, 64));
        float mn = fmaxf(m_r[i][r], mx);
        float al = __expf(m_r[i][r] - mn);
        float ps = 0.f;
        #pragma unroll
        for (int j = 0; j < 4; ++j){
          float p = __expf(sc[i][j][r] - mn);
          sc[i][j][r] = p; ps += p;
        }
        #pragma unroll
        for (int o = 1; o < 16; o <<= 1) ps += __shfl_xor(ps, o, 64);
        l_r[i][r] = l_r[i][r] * al + ps;
        m_r[i][r] = mn;
        #pragma unroll
        for (int j = 0; j < 4; ++j) acc[i][j][r] *= al;
      }
    }

    #pragma unroll
    for (int i = 0; i < 2; ++i)
      #pragma unroll
      for (int j = 0; j < 4; ++j)
        #pragma unroll
        for (int r = 0; r < 4; ++r)
          Pw[(i*16 + lq*4 + r)*72 + j*16 + lr] = f2bf(sc[i][j][r]);

    #pragma unroll
    for (int kq = 0; kq < 2; ++kq){
      bf16x8 pf0 = *(const bf16x8*)(Pw + lr*72        + kq*32 + lq*8);
      bf16x8 pf1 = *(const bf16x8*)(Pw + (16 + lr)*72 + kq*32 + lq*8);
      #pragma unroll
      for (int j = 0; j < 4; ++j){
        bf16x8 vfj = *(const bf16x8*)(Vt + (j*16 + lr)*72 + kq*32 + lq*8);
        acc[0][j] = __builtin_amdgcn_mfma_f32_16x16x32_bf16(pf0, vfj, acc[0][j], 0, 0, 0);
        acc[1][j] = __builtin_amdgcn_mfma_f32_16x16x32_bf16(pf1, vfj, acc[1][j], 0, 0, 0);
      }
    }
    __syncthreads();
  }

  #pragma unroll
  for (int i = 0; i < 2; ++i){
    #pragma unroll
    for (int r = 0; r < 4; ++r){
      float inv = 1.f / l_r[i][r];
      int qg = qrow + i*16 + lq*4 + r;
      u16* hp = h + (size_t)(b*SS + qg)*768 + hh*64;
      #pragma unroll
      for (int j = 0; j < 4; ++j){
        int d = j*16 + lr;
        hp[d] = f2bf(bf2f(hp[d]) + acc[i][j][r] * inv);
      }
    }
  }
}

// ---------------------------------------------------------------- small-N projection (wave/row, LDS W)
template<int NN>
__global__ __launch_bounds__(256) void smalln_k(const u16* __restrict__ A, const void* __restrict__ W,
                         const void* __restrict__ bias, void* __restrict__ out,
                         const int* fl, int outmode){
  int f = *fl;
  __shared__ float Wl[NN*768];
  for (int i = threadIdx.x; i < NN*768; i += 256){
    int n = i / 768, k = i - n*768;
    Wl[i] = ldany(W, (size_t)k*NN + n, f);
  }
  __syncthreads();
  int wave = threadIdx.x >> 6, lane = threadIdx.x & 63;
  int rowbase = blockIdx.x*16 + wave*4;
  for (int r = 0; r < 4; ++r){
    int row = rowbase + r;
    const u16* ap = A + (size_t)row * 768;
    float a[12];
    #pragma unroll
    for (int i = 0; i < 12; ++i) a[i] = bf2f(ap[i*64 + lane]);
    float acc[NN];
    #pragma unroll
    for (int n = 0; n < NN; ++n) acc[n] = 0.f;
    #pragma unroll
    for (int i = 0; i < 12; ++i){
      int k = i*64 + lane;
      #pragma unroll
      for (int n = 0; n < NN; ++n) acc[n] += a[i] * Wl[n*768 + k];
    }
    float red[NN];
    #pragma unroll
    for (int n = 0; n < NN; ++n){
      float v = acc[n];
      #pragma unroll
      for (int o = 32; o > 0; o >>= 1) v += __shfl_down(v, o, 64);
      red[n] = v;
    }
    if (lane == 0){
      #pragma unroll
      for (int n = 0; n < NN; ++n){
        float v = red[n] + ldany(bias, n, f);
        size_t oi = (size_t)row*NN + n;
        if (outmode && f) ((float*)out)[oi] = v;
        else ((u16*)out)[oi] = f2bf(v);
      }
    }
  }
}

// ---------------------------------------------------------------- c path
__global__ void ctrans_k(const u16* __restrict__ in, u16* __restrict__ out){
  int idx = blockIdx.x * 256 + threadIdx.x;   // 2*16*4096
  int b = idx >> 16;
  int r = idx & 65535;
  int d = r >> 12, s = r & 4095;
  out[idx] = in[(size_t)(b*4096 + s)*16 + d];
}

__global__ __launch_bounds__(256) void c2mlp1_k(const u16* __restrict__ ct,
    const void* __restrict__ w, float* __restrict__ yacc, const int* fl){
  int f = *fl;
  __shared__ float Awt[64][36];
  __shared__ u16 Ws[64*128];
  int n0 = blockIdx.x * 128;
  int k0 = blockIdx.y * 512;
  int tid = threadIdx.x;
  int c4 = (tid & 31) * 4;
  int r0 = (tid >> 5) * 4;
  float acc[4][4] = {};
  for (int ks = 0; ks < 512; ks += 64){
    __syncthreads();
    {
      int mm = tid >> 3, kk8 = (tid & 7) * 8;
      uint4 av = *(const uint4*)(ct + (size_t)mm*4096 + k0 + ks + kk8);
      float fv[8] = {bflo(av.x),bfhi(av.x),bflo(av.y),bfhi(av.y),
                     bflo(av.z),bfhi(av.z),bflo(av.w),bfhi(av.w)};
      #pragma unroll
      for (int i = 0; i < 8; ++i) Awt[kk8+i][mm] = fv[i];
    }
    {
      int kk = tid >> 2, cc = (tid & 3) * 32;
      #pragma unroll
      for (int j = 0; j < 32; ++j)
        Ws[kk*128 + cc + j] = f2bf(ldany(w, (size_t)(k0+ks+kk)*4096 + n0 + cc + j, f));
    }
    __syncthreads();
    for (int kk = 0; kk < 64; ++kk){
      float4 a4 = *(const float4*)&Awt[kk][r0];
      uint2 wv = *(const uint2*)(Ws + kk*128 + c4);
      float w0 = bflo(wv.x), w1v = bfhi(wv.x), w2v = bflo(wv.y), w3v = bfhi(wv.y);
      float ar[4] = {a4.x, a4.y, a4.z, a4.w};
      #pragma unroll
      for (int r = 0; r < 4; ++r){
        acc[r][0] += ar[r]*w0;  acc[r][1] += ar[r]*w1v;
        acc[r][2] += ar[r]*w2v; acc[r][3] += ar[r]*w3v;
      }
    }
  }
  #pragma unroll
  for (int r = 0; r < 4; ++r)
    #pragma unroll
    for (int cc = 0; cc < 4; ++cc)
      atomicAdd(&yacc[(size_t)(r0+r)*4096 + n0 + c4 + cc], acc[r][cc]);
}

__global__ void silu_bias_k(const float* __restrict__ yacc, const void* __restrict__ bias,
                            u16* __restrict__ out, const int* fl){
  int f = *fl;
  int idx = blockIdx.x*256 + threadIdx.x;    // 32*4096
  int n = idx & 4095;
  float v = yacc[idx] + ldany(bias, n, f);
  out[idx] = f2bf(v / (1.f + __expf(-v)));
}

__global__ void c2mlp2_k(const u16* __restrict__ y, const void* __restrict__ w2,
                         float* __restrict__ emb_pre, const int* fl){
  int f = *fl;
  int m = blockIdx.x, kseg = blockIdx.y;
  int col = threadIdx.x & 63, sl = threadIdx.x >> 6;
  float acc = 0.f;
  int kb = kseg*512 + sl*128;
  for (int k = kb; k < kb+128; ++k)
    acc += bf2f(y[(size_t)m*4096 + k]) * ldany(w2, (size_t)k*64 + col, f);
  __shared__ float red[256];
  red[threadIdx.x] = acc;
  __syncthreads();
  if (sl == 0){
    float t = red[col] + red[col+64] + red[col+128] + red[col+192];
    int b = m >> 4, d = m & 15;
    atomicAdd(&emb_pre[b*1024 + col*16 + d], t);
  }
}

__global__ void head1_k(const float* __restrict__ emb, const void* __restrict__ w,
                        float* __restrict__ hacc, const int* fl){
  int f = *fl;
  int n = blockIdx.x*256 + threadIdx.x;    // 16384
  int k0 = blockIdx.y*256;
  float a0 = 0.f, a1 = 0.f;
  for (int k = k0; k < k0+256; ++k){
    float wv = ldany(w, (size_t)k*16384 + n, f);
    a0 += emb[k] * wv;
    a1 += emb[1024 + k] * wv;
  }
  atomicAdd(&hacc[n], a0);
  atomicAdd(&hacc[16384 + n], a1);
}

__global__ void head1fin_k(const float* __restrict__ hacc, const void* __restrict__ bias,
                           void* __restrict__ out, const int* fl){
  int f = *fl;
  int n = blockIdx.x*256 + threadIdx.x;
  float b = ldany(bias, n, f);
  float a0 = hacc[n] + b, a1 = hacc[16384 + n] + b;
  if (f){ ((float*)out)[32768 + n] = a0; ((float*)out)[49152 + n] = a1; }
  else  { ((u16*)out)[32768 + n] = f2bf(a0); ((u16*)out)[49152 + n] = f2bf(a1); }
}

// ================================================================ host
extern "C" void kernel_launch(void* const* d_in, const int* in_sizes, int n_in,
                              void* d_out, int out_size, void* d_ws, size_t ws_size,
                              hipStream_t stream)
{
  const int* x   = (const int*)d_in[0];
  const int* idv = (const int*)d_in[1];
  const void* embt = d_in[2];
  const void* cd_w = d_in[3];
  const void* cd_b = d_in[4];
  const void* wq = d_in[5];
  const void* bq = d_in[6];
  const void* wk = d_in[7];
  const void* bk = d_in[8];
  const void* wv = d_in[9];
  const void* bv = d_in[10];
  const void* attn_nw = d_in[11];
  const void* ffn_nw  = d_in[12];
  const void* w1 = d_in[13];
  const void* b1 = d_in[14];
  const void* w2 = d_in[15];
  const void* b2 = d_in[16];
  const void* w3 = d_in[17];
  const void* b3 = d_in[18];
  const void* h0_w1 = d_in[19];
  const void* h0_b1 = d_in[20];
  const void* h0_w2 = d_in[21];
  const void* h0_b2 = d_in[22];
  const void* nh0_w = d_in[23];
  const void* head0_w = d_in[24];
  const void* head0_b = d_in[25];
  const void* c1_w1 = d_in[26];
  const void* c1_b1 = d_in[27];
  const void* c1_w2 = d_in[28];
  const void* c1_b2 = d_in[29];
  const void* c2_w1 = d_in[30];
  const void* c2_b1 = d_in[31];
  const void* c2_w2 = d_in[32];
  const void* c2_b2 = d_in[33];
  const void* nemb_w = d_in[34];
  const void* head1_w = d_in[35];
  const void* head1_b = d_in[36];

  char* ws = (char*)d_ws;
  size_t off = 0;
  auto alloc = [&](size_t bytes)->char*{
    char* p = ws + off; off = (off + bytes + 255) & ~(size_t)255; return p;
  };

  int*  flag  = (int*)alloc(256);
  u16*  wtbuf = (u16*)alloc((size_t)(2304+2048)*768*2); // transposed-weight buffers (bf16)
  u16*  wt2nd = wtbuf + (size_t)2048*768;               // second slot (w3) — overlaps QKV region tail-safely (sequential use)
  u16*  h     = (u16*)alloc((size_t)NROWS*768*2);       // residual stream bf16
  u16*  fbuf  = (u16*)alloc((size_t)NROWS*768*2);       // normed activations bf16
  char* R3    = alloc((size_t)NROWS*768*2*3);           // 37.75MB union scratch

  u16* xin  = (u16*)R3;                                  // (8192,288)
  u16* qkvb = (u16*)R3;                                  // (8192,2304) fused QKV
  u16* g1   = (u16*)R3;                                  // (8192,2048)
  u16* tbuf = (u16*)R3;                                  // (8192,768)
  u16* gbuf = (u16*)(R3 + (size_t)NROWS*768*2);          // (8192,768)
  char* tail = R3 + (size_t)NROWS*768*2*2;
  u16* cbuf = (u16*)tail;                                // (8192,16)
  u16* ctb  = (u16*)(tail + 262144);                     // (32,4096)
  float* yacc = (float*)(tail + 262144*2);               // (32,4096) f32
  u16* ybf  = (u16*)(tail + 262144*2 + 524288);          // (32,4096)
  float* emb_pre = (float*)(tail + 262144*3 + 524288);   // (2,1024) f32
  float* embn    = (float*)(tail + 262144*3 + 524288 + 8192);
  float* hacc    = (float*)(tail + 262144*3 + 524288 + 16384); // (2,16384) f32

  detect_k<<<1, 64, 0, stream>>>(attn_nw, flag);

  auto tr = [&](const void* src, size_t ioff, u16* dst, int R, int C){
    dim3 g((C+31)/32, (R+31)/32);
    transpose_k<<<g, 256, 0, stream>>>(src, ioff, dst, R, C, flag);
  };
  auto gemm = [&](const u16* A, const u16* BT, const void* bias, int boff,
                  u16* out_, int M, int N, int K, int epi){
    dim3 g(N/128, M/128);
    gemm_bt_k<<<g, 256, 0, stream>>>(A, BT, bias, nullptr, nullptr, boff,
                                     out_, M, N, K, epi, flag);
  };

  // embed + concat-id -> xin;  h = xin @ cd_w + cd_b
  embed_k<<<NROWS, 256, 0, stream>>>(x, idv, embt, xin, flag);
  tr(cd_w, 0, wtbuf, 288, 768);
  gemm(xin, wtbuf, cd_b, 0, h, NROWS, 768, 288, 0);

  for (int l = 0; l < 4; ++l){
    size_t wo = (size_t)l*768*768, fo = (size_t)l*768*2048;
    // attn: fbuf = rmsnorm(h, attn_nw); qkv = fbuf @ [wq wk wv] + biases
    rmsnormw_k<<<NROWS/4, 256, 0, stream>>>(h, attn_nw, l*768, fbuf, flag);
    transpose_qkv_k<<<dim3(24,24,3), 256, 0, stream>>>(wq, wk, wv, wo, wtbuf, flag);
    {
      dim3 g(2304/128, NROWS/128);
      gemm_bt_k<<<g, 256, 0, stream>>>(fbuf, wtbuf, bq, bk, bv, l*768,
                                       qkvb, NROWS, 2304, 768, 0, flag);
    }
    attn_mfma_k<<<dim3(32,12,2), 256, 0, stream>>>(qkvb, h);

    // ffn
    rmsnormw_k<<<NROWS/4, 256, 0, stream>>>(h, ffn_nw, l*768, fbuf, flag);
    tr(w1, fo, wtbuf, 768, 2048);
    tr(w3, fo, wt2nd, 768, 2048);
    gemm(fbuf, wtbuf, b1, l*2048, g1, NROWS, 2048, 768, 0);
    gemm(fbuf, wt2nd, b3, l*2048, g1, NROWS, 2048, 768, 2);  // in-place gate
    tr(w2, fo, wtbuf, 2048, 768);
    gemm(g1, wtbuf, b2, l*768, h, NROWS, 768, 2048, 3);      // residual
  }

  // head0 path
  tr(h0_w1, 0, wtbuf, 768, 768);
  gemm(h, wtbuf, h0_b1, 0, gbuf, NROWS, 768, 768, 1);
  tr(h0_w2, 0, wtbuf, 768, 768);
  gemm(gbuf, wtbuf, h0_b2, 0, tbuf, NROWS, 768, 768, 0);
  rmsnormw_k<<<NROWS/4, 256, 0, stream>>>(tbuf, nh0_w, 0, gbuf, flag);
  smalln_k<4><<<NROWS/16, 256, 0, stream>>>(gbuf, head0_w, head0_b, d_out, flag, 1);

  // c path
  tr(c1_w1, 0, wtbuf, 768, 768);
  gemm(h, wtbuf, c1_b1, 0, gbuf, NROWS, 768, 768, 1);
  smalln_k<16><<<NROWS/16, 256, 0, stream>>>(gbuf, c1_w2, c1_b2, cbuf, flag, 0);
  ctrans_k<<<512, 256, 0, stream>>>(cbuf, ctb);
  hipMemsetAsync(yacc, 0, (size_t)32*4096*4, stream);
  hipMemsetAsync(emb_pre, 0, 2*1024*4, stream);
  hipMemsetAsync(hacc, 0, (size_t)2*16384*4, stream);
  c2mlp1_k<<<dim3(32,8), 256, 0, stream>>>(ctb, c2_w1, yacc, flag);
  silu_bias_k<<<512, 256, 0, stream>>>(yacc, c2_b1, ybf, flag);
  c2mlp2_k<<<dim3(32,8), 256, 0, stream>>>(ybf, c2_w2, emb_pre, flag);
  rmsnorm_emb_k<<<2, 256, 0, stream>>>(emb_pre, c2_b2, nemb_w, embn, flag);
  head1_k<<<dim3(64,4), 256, 0, stream>>>(embn, head1_w, hacc, flag);
  head1fin_k<<<64, 256, 0, stream>>>(hacc, head1_b, d_out, flag);

  (void)in_sizes; (void)n_in; (void)out_size; (void)ws_size;
}